// Round 5
// baseline (1008.695 us; speedup 1.0000x reference)
//
#include <hip/hip_runtime.h>
#include <hip/hip_bf16.h>
#include <cstdint>

// ---------------------------------------------------------------------------
// SquashedGaussianMoEActor forward, MI355X (gfx950).
// Split-f16 MFMA (hi/lo pairs, 3x v_mfma_f32_16x16x32_f16) = fp32-quality.
// Attention folded: score = t1.(eW2@K@q), vals = t1@(eW2@V); eo never built.
// R5: 8-wave 128x128 double-buffered GEMM (stage-next-early, 1 barrier/tile,
// setprio on MFMA cluster); mixture reg-stages A with fused softmax scaling.
// B=8192, OBS=128, H=D=512, E=16, T=50, A=32.
// ---------------------------------------------------------------------------

typedef _Float16 f16;
typedef _Float16 f16x4 __attribute__((ext_vector_type(4)));
typedef _Float16 f16x8 __attribute__((ext_vector_type(8)));
typedef float f32x4 __attribute__((ext_vector_type(4)));

__device__ __forceinline__ void fsplit(float x, f16& h, f16& l) {
    h = (f16)x;
    l = (f16)(x - (float)h);
}

__device__ __forceinline__ void gload16(const void* g, void* s) {
    __builtin_amdgcn_global_load_lds(
        (const __attribute__((address_space(1))) void*)g,
        (__attribute__((address_space(3))) void*)s, 16, 0, 0);
}

// --- elementwise fp32 -> f16 pair split -----------------------------------
__global__ void split_pairs(const float* __restrict__ x, f16* __restrict__ h,
                            f16* __restrict__ l, int n4) {
    int i = blockIdx.x * 256 + threadIdx.x;
    if (i >= n4) return;
    float4 v = ((const float4*)x)[i];
    float a[4] = {v.x, v.y, v.z, v.w};
    f16x4 hh, ll;
#pragma unroll
    for (int j = 0; j < 4; ++j) { f16 hj, lj; fsplit(a[j], hj, lj); hh[j] = hj; ll[j] = lj; }
    *(f16x4*)&h[(long)i * 4] = hh;
    *(f16x4*)&l[(long)i * 4] = ll;
}

// --- transpose [K,N] fp32 -> [N,K] f16 pairs (batched via z) ---------------
__global__ void transpose_split(const float* __restrict__ W, f16* __restrict__ Th,
                                f16* __restrict__ Tl, int K, int N, long ist, long ost) {
    __shared__ float t[32][33];
    const float* Wb = W + (long)blockIdx.z * ist;
    const int k0 = blockIdx.x * 32, n0 = blockIdx.y * 32;
    const int tid = threadIdx.x;
    const int r = tid >> 3, c4 = (tid & 7) * 4;
    float4 v = *(const float4*)&Wb[(long)(k0 + r) * N + n0 + c4];
    t[r][c4] = v.x; t[r][c4 + 1] = v.y; t[r][c4 + 2] = v.z; t[r][c4 + 3] = v.w;
    __syncthreads();
    f16x4 hh, ll;
#pragma unroll
    for (int j = 0; j < 4; ++j) { f16 hj, lj; fsplit(t[c4 + j][r], hj, lj); hh[j] = hj; ll[j] = lj; }
    long ob = (long)blockIdx.z * ost + (long)(n0 + r) * K + k0 + c4;
    *(f16x4*)&Th[ob] = hh;
    *(f16x4*)&Tl[ob] = ll;
}

// --- W2T[half][col][k]: [0]=mW2^T, [1]=lW2^T (f32) -------------------------
__global__ void build_w2t(const float* __restrict__ mW2, const float* __restrict__ lW2,
                          float* __restrict__ W2T) {
    const int i = blockIdx.x * 256 + threadIdx.x;  // 32768
    const int half = i >> 14, col = (i >> 9) & 31, k = i & 511;
    const float* src = half ? lW2 : mW2;
    W2T[i] = src[k * 32 + col];
}

// --- bcat = [mb1 ; lb1] ----------------------------------------------------
__global__ void build_bcat(const float* __restrict__ mb1, const float* __restrict__ lb1,
                           float* __restrict__ bcat) {
    const int i = blockIdx.x * 256 + threadIdx.x;  // 1024
    bcat[i] = (i < 512) ? mb1[i] : lb1[i - 512];
}

// --- split-f16 GEMM, double-buffered 8-wave 128x128 tile, BK=64 ------------
// A: [M,K] pairs. B stored transposed: [N,K] pairs. LDS dbuf, stage-next
// before compute, single __syncthreads per K-tile (vmcnt drain overlapped).
// OUTM: 0 pair write, 1 pair write transposed, 2 f32 write, 3 f32 accum,
//       5 score mode (row-dot KQ2 -> atomicAdd) + write t1 single-f16 (U).
// ASINGLE: A single plane, reg-staged with per-(row,ktile) wscale (mixture).
template <int OUTM, bool RELU, bool ASINGLE>
__global__ __launch_bounds__(512, 2) void gemm_pair(
    const f16* __restrict__ Ah, const f16* __restrict__ Al, int lda, long zsA,
    const f16* __restrict__ Bh, const f16* __restrict__ Bl, int ldb, long zsB,
    const float* __restrict__ bias, long zsBias,
    f16* __restrict__ Ch, f16* __restrict__ Cl, float* __restrict__ Cf,
    int ldc, long zsC, int K,
    const float* __restrict__ wscale,
    const int* __restrict__ task, const float* __restrict__ KQ2,
    float* __restrict__ scores) {
    constexpr int APL = ASINGLE ? 1 : 2;
    __shared__ f16 AsBuf[2 * APL * 128 * 64];   // [buf][plane][128][64]
    __shared__ f16 BsBuf[2 * 2 * 128 * 64];     // [buf][plane][128][64]
    const int z = blockIdx.z;
    Ah += (long)z * zsA;
    if constexpr (!ASINGLE) Al += (long)z * zsA;
    Bh += (long)z * zsB; Bl += (long)z * zsB;
    if (bias) bias += (long)z * zsBias;
    if (OUTM <= 1) { Ch += (long)z * zsC; Cl += (long)z * zsC; }
    if (OUTM == 2 || OUTM == 3) { Cf += (long)z * zsC; }
    const int tid = threadIdx.x;
    const int l = tid & 63;
    const int w = tid >> 6;
    const int row0 = blockIdx.x * 128;
    const int col0 = blockIdx.y * 128;
    const int wrow = (w >> 2) * 64;   // wave output: 64 rows x 32 cols
    const int wcol = (w & 3) * 32;
    const int srow = tid >> 3;        // staging row 0..63 (+64 for half 1)
    const int schunk = tid & 7;       // staging 16B chunk

    auto Aidx = [&](int buf, int p, int r, int c) {
        return ((buf * APL + p) * 128 + r) * 64 + c;
    };
    auto Bidx = [&](int buf, int p, int r, int c) {
        return ((buf * 2 + p) * 128 + r) * 64 + c;
    };

    f32x4 acc[4][2];
#pragma unroll
    for (int mi = 0; mi < 4; ++mi)
#pragma unroll
        for (int ni = 0; ni < 2; ++ni)
#pragma unroll
            for (int j = 0; j < 4; ++j) acc[mi][ni][j] = 0.f;

    // ---- staging helpers ----
    auto stageB = [&](int buf, int k0) {
#pragma unroll
        for (int p = 0; p < 2; ++p) {
            const f16* src = p ? Bl : Bh;
#pragma unroll
            for (int h = 0; h < 2; ++h) {
                const int r = h * 64 + srow;
                gload16(src + (long)(col0 + r) * ldb + k0 + ((schunk ^ (r & 7)) << 3),
                        &BsBuf[Bidx(buf, p, h * 64 + (w << 3), 0)]);
            }
        }
    };
    auto stageA = [&](int buf, int k0) {   // pair path (gload_lds)
#pragma unroll
        for (int p = 0; p < APL; ++p) {
            const f16* src = p ? Al : Ah;
#pragma unroll
            for (int h = 0; h < 2; ++h) {
                const int r = h * 64 + srow;
                gload16(src + (long)(row0 + r) * lda + k0 + ((schunk ^ (r & 7)) << 3),
                        &AsBuf[Aidx(buf, p, h * 64 + (w << 3), 0)]);
            }
        }
    };
    // ASINGLE: reg-staged A with fused per-(row, ktile) scale
    uint4 areg0, areg1; float ascl0, ascl1;
    auto ldA = [&](int k0) {
        const int r0 = srow, r1 = 64 + srow;
        areg0 = *(const uint4*)&Ah[(long)(row0 + r0) * lda + k0 + (schunk << 3)];
        areg1 = *(const uint4*)&Ah[(long)(row0 + r1) * lda + k0 + (schunk << 3)];
        const int e = k0 >> 9;
        ascl0 = wscale[(long)(row0 + r0) * 16 + e];
        ascl1 = wscale[(long)(row0 + r1) * 16 + e];
    };
    auto wrA = [&](int buf) {
#pragma unroll
        for (int h = 0; h < 2; ++h) {
            const int r = h * 64 + srow;
            const float s = h ? ascl1 : ascl0;
            f16x8 v = h ? *(f16x8*)&areg1 : *(f16x8*)&areg0;
#pragma unroll
            for (int j = 0; j < 8; ++j) v[j] = (f16)((float)v[j] * s);
            *(uint4*)&AsBuf[Aidx(buf, 0, r, (schunk ^ (r & 7)) << 3)] = *(uint4*)&v;
        }
    };

    auto compute = [&](int buf) {
        const int r16 = l & 15, kg = l >> 4;
#pragma unroll
        for (int ks = 0; ks < 2; ++ks) {
            f16x8 a_h[4], a_l[4], b_h[2], b_l[2];
#pragma unroll
            for (int mi = 0; mi < 4; ++mi) {
                const int r = wrow + mi * 16 + r16;
                const int off = ((ks * 4 + kg) ^ (r & 7)) << 3;
                a_h[mi] = *(const f16x8*)&AsBuf[Aidx(buf, 0, r, off)];
                if constexpr (!ASINGLE) a_l[mi] = *(const f16x8*)&AsBuf[Aidx(buf, 1, r, off)];
            }
#pragma unroll
            for (int ni = 0; ni < 2; ++ni) {
                const int c = wcol + ni * 16 + r16;
                const int off = ((ks * 4 + kg) ^ (c & 7)) << 3;
                b_h[ni] = *(const f16x8*)&BsBuf[Bidx(buf, 0, c, off)];
                b_l[ni] = *(const f16x8*)&BsBuf[Bidx(buf, 1, c, off)];
            }
            __builtin_amdgcn_s_setprio(1);
#pragma unroll
            for (int mi = 0; mi < 4; ++mi)
#pragma unroll
                for (int ni = 0; ni < 2; ++ni) {
                    acc[mi][ni] = __builtin_amdgcn_mfma_f32_16x16x32_f16(a_h[mi], b_h[ni], acc[mi][ni], 0, 0, 0);
                    acc[mi][ni] = __builtin_amdgcn_mfma_f32_16x16x32_f16(a_h[mi], b_l[ni], acc[mi][ni], 0, 0, 0);
                    if constexpr (!ASINGLE)
                        acc[mi][ni] = __builtin_amdgcn_mfma_f32_16x16x32_f16(a_l[mi], b_h[ni], acc[mi][ni], 0, 0, 0);
                }
            __builtin_amdgcn_s_setprio(0);
        }
    };

    // ---- prologue: stage tile 0 ----
    if constexpr (ASINGLE) { ldA(0); stageB(0, 0); wrA(0); }
    else { stageA(0, 0); stageB(0, 0); }
    __syncthreads();
    int cur = 0;
    for (int k0 = 0; k0 < K; k0 += 64) {
        const bool nxt = (k0 + 64) < K;
        if constexpr (ASINGLE) {
            if (nxt) { ldA(k0 + 64); stageB(cur ^ 1, k0 + 64); }
            compute(cur);
            if (nxt) wrA(cur ^ 1);
        } else {
            if (nxt) { stageA(cur ^ 1, k0 + 64); stageB(cur ^ 1, k0 + 64); }
            compute(cur);
        }
        __syncthreads();
        cur ^= 1;
    }

    // ---- epilogue. C layout (m89): col = lane&15, row = (lane>>4)*4 + reg.
    const int lane15 = l & 15;
    const int rsub = (l >> 4) * 4;
    if (OUTM == 5) {
        const int expert = col0 >> 9;
        float bv[2];
#pragma unroll
        for (int ni = 0; ni < 2; ++ni)
            bv[ni] = bias ? bias[col0 + wcol + ni * 16 + lane15] : 0.f;
#pragma unroll
        for (int mi = 0; mi < 4; ++mi)
#pragma unroll
            for (int j = 0; j < 4; ++j) {
                const int rowg = row0 + wrow + mi * 16 + rsub + j;
                const int t = task[rowg];
                const float* kqr = KQ2 + ((long)t * 16 + expert) * 512;
                float part = 0.f;
#pragma unroll
                for (int ni = 0; ni < 2; ++ni) {
                    const int colg = col0 + wcol + ni * 16 + lane15;
                    float v = acc[mi][ni][j] + bv[ni];
                    if (RELU) v = fmaxf(v, 0.f);
                    Ch[(long)rowg * ldc + colg] = (f16)v;
                    part += v * kqr[colg & 511];
                }
#pragma unroll
                for (int d = 1; d < 16; d <<= 1) part += __shfl_xor(part, d);
                if (lane15 == 0) atomicAdd(&scores[rowg * 16 + expert], part);
            }
    } else {
#pragma unroll
        for (int mi = 0; mi < 4; ++mi)
#pragma unroll
            for (int ni = 0; ni < 2; ++ni) {
                const int colg = col0 + wcol + ni * 16 + lane15;
                const float bv = bias ? bias[colg] : 0.f;
#pragma unroll
                for (int j = 0; j < 4; ++j) {
                    const int rowg = row0 + wrow + mi * 16 + rsub + j;
                    float v = acc[mi][ni][j] + bv;
                    if (RELU) v = fmaxf(v, 0.f);
                    if (OUTM == 0) {
                        f16 hh, ll; fsplit(v, hh, ll);
                        const long idx = (long)rowg * ldc + colg;
                        Ch[idx] = hh; Cl[idx] = ll;
                    } else if (OUTM == 1) {
                        f16 hh, ll; fsplit(v, hh, ll);
                        const long idx = (long)colg * ldc + rowg;
                        Ch[idx] = hh; Cl[idx] = ll;
                    } else if (OUTM == 2) {
                        Cf[(long)rowg * ldc + colg] = v;
                    } else if (OUTM == 3) {
                        Cf[(long)rowg * ldc + colg] += v;
                    }
                }
            }
    }
}

// --- KQ2[t][e][i] = sum_j Wrows[e*512+i][j] * tq[t][j]  (fp32) -------------
__global__ void kq_kernel(const float* __restrict__ Wrows, const float* __restrict__ tq,
                          float* __restrict__ KQ) {
    __shared__ float qt[25][512];
    const int tid = threadIdx.x;
    const int l = tid & 63, w = tid >> 6;
    const int wave_g = blockIdx.x * 4 + w;
    for (int tile = 0; tile < 2; ++tile) {
        __syncthreads();
        for (int i = tid; i < 25 * 512; i += 256)
            qt[i >> 9][i & 511] = tq[(long)(tile * 25 + (i >> 9)) * 512 + (i & 511)];
        __syncthreads();
        for (int rr = 0; rr < 4; ++rr) {
            const int row = wave_g * 4 + rr;  // 0..8191 = e*512 + i
            const int e = row >> 9, i0 = row & 511;
            float kv[8];
            const float* kp = Wrows + (long)row * 512 + l * 8;
#pragma unroll
            for (int j = 0; j < 8; ++j) kv[j] = kp[j];
#pragma unroll
            for (int tt = 0; tt < 25; ++tt) {
                float s = 0.f;
#pragma unroll
                for (int j = 0; j < 8; ++j) s += kv[j] * qt[tt][l * 8 + j];
#pragma unroll
                for (int d = 1; d < 64; d <<= 1) s += __shfl_xor(s, d);
                if (l == tt) KQ[((long)(tile * 25 + tt) * 16 + e) * 512 + i0] = s;
            }
        }
    }
}

// --- out[e*512+j] = sum_k bvec[e*512+k] * M[e][k][j] -----------------------
__global__ void bias_fold(const float* __restrict__ bvec, const float* __restrict__ M,
                          float* __restrict__ out) {
    const int gid = blockIdx.x * 256 + threadIdx.x;  // 8192
    const int e = gid >> 9, j = gid & 511;
    const float* Me = M + (long)e * 262144;
    const float* be = bvec + e * 512;
    float s = 0.f;
    for (int k = 0; k < 512; ++k) s += be[k] * Me[(long)k * 512 + j];
    out[gid] = s;
}

// --- cb[t][e] = dot(bK[e,:], tq[t,:]) --------------------------------------
__global__ void cb_kernel(const float* __restrict__ bK, const float* __restrict__ tq,
                          float* __restrict__ cb) {
    const int gw = (blockIdx.x * 256 + threadIdx.x) >> 6;  // 0..799
    const int l = threadIdx.x & 63;
    const int t = gw >> 4, e = gw & 15;
    const float* a = bK + e * 512 + l * 8;
    const float* q = tq + (long)t * 512 + l * 8;
    float s = 0.f;
#pragma unroll
    for (int j = 0; j < 8; ++j) s += a[j] * q[j];
#pragma unroll
    for (int d = 1; d < 64; d <<= 1) s += __shfl_xor(s, d);
    if (l == 0) cb[t * 16 + e] = s;
}

// --- scores[b*16+e] = cb[task[b]*16+e] -------------------------------------
__global__ void scores_init(const int* __restrict__ task, const float* __restrict__ cb,
                            float* __restrict__ sc) {
    const int i = blockIdx.x * 256 + threadIdx.x;  // 131072
    sc[i] = cb[task[i >> 4] * 16 + (i & 15)];
}

// --- in-place softmax over E=16 per row ------------------------------------
__global__ void softmax16(float* __restrict__ sc) {
    const int b = blockIdx.x * 256 + threadIdx.x;  // 8192
    float v[16];
    const float4* pp = (const float4*)&sc[b * 16];
#pragma unroll
    for (int qq = 0; qq < 4; ++qq) {
        float4 t = pp[qq];
        v[qq * 4] = t.x; v[qq * 4 + 1] = t.y; v[qq * 4 + 2] = t.z; v[qq * 4 + 3] = t.w;
    }
    float m = v[0];
#pragma unroll
    for (int e = 1; e < 16; ++e) m = fmaxf(m, v[e]);
    float ssum = 0.f;
#pragma unroll
    for (int e = 0; e < 16; ++e) { v[e] = expf(v[e] - m); ssum += v[e]; }
    const float inv = 1.f / ssum;
    float4* o = (float4*)&sc[b * 16];
#pragma unroll
    for (int qq = 0; qq < 4; ++qq) {
        float4 t;
        t.x = v[qq * 4] * inv; t.y = v[qq * 4 + 1] * inv;
        t.z = v[qq * 4 + 2] * inv; t.w = v[qq * 4 + 3] * inv;
        o[qq] = t;
    }
}

// --- towerAcc[b][j] = sum_e w[b][e] * b2V[e][j] ----------------------------
__global__ void wb_init(const float* __restrict__ w, const float* __restrict__ b2V,
                        float* __restrict__ towerAcc) {
    const int b = blockIdx.x;
    const int tid = threadIdx.x;
    float wv[16];
#pragma unroll
    for (int e = 0; e < 16; ++e) wv[e] = w[b * 16 + e];
#pragma unroll
    for (int rep = 0; rep < 2; ++rep) {
        const int j = rep * 256 + tid;
        float s = 0.f;
#pragma unroll
        for (int e = 0; e < 16; ++e) s += wv[e] * b2V[e * 512 + j];
        towerAcc[(long)b * 512 + j] = s;
    }
}

// --- final heads: GEMV vs W2T (float4 streams), squash, logp ---------------
__global__ void head_kernel2(
    const f16* __restrict__ Rh, const f16* __restrict__ Rl,
    const float* __restrict__ W2T,   // [2][32][512]
    const float* __restrict__ mb2, const float* __restrict__ lb2,
    const float* __restrict__ eps, float* __restrict__ pi, float* __restrict__ logp) {
    __shared__ float src[4][1032];
    const int tid = threadIdx.x, l = tid & 63, w = tid >> 6;
    const int b = blockIdx.x * 4 + w;  // one wave per row
    const long rb = (long)b * 1024;
    {
        f16x8 h0 = *(const f16x8*)&Rh[rb + l * 8];
        f16x8 l0 = *(const f16x8*)&Rl[rb + l * 8];
        f16x8 h1 = *(const f16x8*)&Rh[rb + 512 + l * 8];
        f16x8 l1 = *(const f16x8*)&Rl[rb + 512 + l * 8];
#pragma unroll
        for (int j = 0; j < 8; ++j) {
            src[w][l * 8 + j] = (float)h0[j] + (float)l0[j];
            src[w][512 + l * 8 + j] = (float)h1[j] + (float)l1[j];
        }
    }
    __syncthreads();
    const int col = l & 31;
    const int half = l >> 5;  // 0 = mu, 1 = log_std
    const float4* wp = (const float4*)(W2T + ((long)(half * 32 + col)) * 512);
    const float4* sp = (const float4*)(&src[w][half * 512]);
    float a0 = 0.f, a1 = 0.f, a2 = 0.f, a3 = 0.f;
#pragma unroll 8
    for (int k4 = 0; k4 < 128; ++k4) {
        const float4 wv = wp[k4];
        const float4 sv = sp[k4];
        a0 = fmaf(wv.x, sv.x, a0);
        a1 = fmaf(wv.y, sv.y, a1);
        a2 = fmaf(wv.z, sv.z, a2);
        a3 = fmaf(wv.w, sv.w, a3);
    }
    const float* b2 = half ? lb2 : mb2;
    float s = b2[col] + ((a0 + a1) + (a2 + a3));
    const float other = __shfl_xor(s, 32);  // swap mu <-> log_std halves
    if (half == 0) {
        const float mu = s;
        float ls = fminf(fmaxf(other, -20.f), 2.f);
        const float e = eps[(long)b * 32 + col];
        const float a = mu + expf(ls) * e;
        float lt = -0.5f * e * e - ls - 0.91893853320467274f;  // -0.5*log(2*pi)
        const float x = -2.f * a;
        const float sp2 = fmaxf(x, 0.f) + log1pf(expf(-fabsf(x)));
        lt -= 2.f * (0.69314718055994531f - a - sp2);
        pi[(long)b * 32 + col] = tanhf(a);
        float r = lt;
#pragma unroll
        for (int d = 1; d < 32; d <<= 1) r += __shfl_xor(r, d);
        if (col == 0) logp[b] = r;
    }
}

// ---------------------------------------------------------------------------
extern "C" void kernel_launch(void* const* d_in, const int* in_sizes, int n_in,
                              void* d_out, int out_size, void* d_ws, size_t ws_size,
                              hipStream_t stream) {
    const float* obs = (const float*)d_in[0];
    const int* task = (const int*)d_in[1];
    const float* eps = (const float*)d_in[2];
    const float* bW1 = (const float*)d_in[3];
    const float* bb1 = (const float*)d_in[4];
    const float* bW2 = (const float*)d_in[5];
    const float* bb2 = (const float*)d_in[6];
    const float* eW1 = (const float*)d_in[7];
    const float* eb1 = (const float*)d_in[8];
    const float* eW2 = (const float*)d_in[9];
    const float* eb2 = (const float*)d_in[10];
    const float* keyM = (const float*)d_in[11];
    const float* valM = (const float*)d_in[12];
    const float* tq = (const float*)d_in[13];
    const float* mW1 = (const float*)d_in[14];
    const float* mb1 = (const float*)d_in[15];
    const float* mW2 = (const float*)d_in[16];
    const float* mb2 = (const float*)d_in[17];
    const float* lW1 = (const float*)d_in[18];
    const float* lb1 = (const float*)d_in[19];
    const float* lW2 = (const float*)d_in[20];
    const float* lb2 = (const float*)d_in[21];
    (void)in_sizes; (void)n_in; (void)out_size; (void)ws_size;

    // ---- workspace map (base 122 MB + 128 MB U; ws >= 251 MB verified R4) --
    const size_t MB = 1u << 20, KB = 1u << 10;
    char* base = (char*)d_ws;
    f16* eW1t_h = (f16*)(base + 0 * MB);   f16* eW1t_l = (f16*)(base + 8 * MB);
    f16* Wv2_h  = (f16*)(base + 16 * MB);  f16* Wv2_l  = (f16*)(base + 24 * MB);  // [j2][(e,i)]
    f16* eW2s_h = (f16*)(base + 32 * MB);  f16* eW2s_l = (f16*)(base + 40 * MB);
    f16* h2_h   = (f16*)(base + 32 * MB);  f16* h2_l   = (f16*)(base + 40 * MB);  // after folds
    f16* Kt_h   = (f16*)(base + 48 * MB);  f16* Kt_l   = (f16*)(base + 56 * MB);
    f16* t1_h   = (f16*)(base + 48 * MB);  f16* t1_l   = (f16*)(base + 56 * MB);  // after WK fold
    f16* Rcat_l = (f16*)(base + 48 * MB);                                         // heads (t1 dead)
    f16* Vt_h   = (f16*)(base + 64 * MB);  f16* Vt_l   = (f16*)(base + 72 * MB);
    f16* Rcat_h = (f16*)(base + 64 * MB);                                         // heads (Vt dead)
    float* WK       = (float*)(base + 80 * MB);
    float* towerAcc = (float*)(base + 80 * MB);  // after kq_kernel
    f16* twP_h  = (f16*)(base + 96 * MB);  f16* twP_l  = (f16*)(base + 104 * MB);
    f16* obs_h  = (f16*)(base + 112 * MB); f16* obs_l  = (f16*)(base + 114 * MB);
    char* q = base + 116 * MB;
    f16* bW1t_h = (f16*)q; q += 128 * KB;  f16* bW1t_l = (f16*)q; q += 128 * KB;
    f16* bW2t_h = (f16*)q; q += 512 * KB;  f16* bW2t_l = (f16*)q; q += 512 * KB;
    // order m_h, l_h, m_l, l_l so the z=2 head GEMM can stride (zsB = 262144)
    f16* mW1t_h = (f16*)q; q += 512 * KB;
    f16* lW1t_h = (f16*)q; q += 512 * KB;
    f16* mW1t_l = (f16*)q; q += 512 * KB;
    f16* lW1t_l = (f16*)q; q += 512 * KB;
    float* KQ2    = (float*)q; q += 1600 * KB;   // 50*16*512 f32
    float* scores = (float*)q; q += 512 * KB;    // 8192*16 f32 (becomes w)
    float* bK     = (float*)q; q += 32 * KB;
    float* b2V    = (float*)q; q += 32 * KB;
    float* cb     = (float*)q; q += 16 * KB;
    float* W2T    = (float*)q; q += 128 * KB;    // [2][32][512]
    float* bcat   = (float*)q; q += 16 * KB;     // [2][512]
    f16* U = (f16*)(base + 122 * MB);            // [8192][8192] single f16

    const long EST = 262144;  // per-expert 512x512 stride
    const size_t LDS_PAIR = 0;  // static shared; no dynamic bytes

    // ---- 1) splits / transposes ----
    split_pairs<<<1024, 256, 0, stream>>>(obs, obs_h, obs_l, 262144);
    split_pairs<<<4096, 256, 0, stream>>>(eW2, eW2s_h, eW2s_l, 1048576);
    transpose_split<<<dim3(4, 16, 1), 256, 0, stream>>>(bW1, bW1t_h, bW1t_l, 128, 512, 0, 0);
    transpose_split<<<dim3(16, 16, 1), 256, 0, stream>>>(bW2, bW2t_h, bW2t_l, 512, 512, 0, 0);
    transpose_split<<<dim3(16, 16, 1), 256, 0, stream>>>(mW1, mW1t_h, mW1t_l, 512, 512, 0, 0);
    transpose_split<<<dim3(16, 16, 1), 256, 0, stream>>>(lW1, lW1t_h, lW1t_l, 512, 512, 0, 0);
    transpose_split<<<dim3(16, 16, 16), 256, 0, stream>>>(eW1, eW1t_h, eW1t_l, 512, 512, EST, EST);
    transpose_split<<<dim3(16, 16, 16), 256, 0, stream>>>(keyM, Kt_h, Kt_l, 512, 512, EST, EST);
    transpose_split<<<dim3(16, 16, 16), 256, 0, stream>>>(valM, Vt_h, Vt_l, 512, 512, EST, EST);
    build_w2t<<<128, 256, 0, stream>>>(mW2, lW2, W2T);
    build_bcat<<<4, 256, 0, stream>>>(mb1, lb1, bcat);

    // ---- 2) attention folds ----
    gemm_pair<2, false, false><<<dim3(4, 4, 16), 512, LDS_PAIR, stream>>>(
        eW2s_h, eW2s_l, 512, EST, Kt_h, Kt_l, 512, EST, nullptr, 0,
        nullptr, nullptr, WK, 512, EST, 512, nullptr, nullptr, nullptr, nullptr);
    gemm_pair<1, false, false><<<dim3(4, 4, 16), 512, LDS_PAIR, stream>>>(
        eW2s_h, eW2s_l, 512, EST, Vt_h, Vt_l, 512, EST, nullptr, 0,
        Wv2_h, Wv2_l, nullptr, 8192, 512, 512, nullptr, nullptr, nullptr, nullptr);
    kq_kernel<<<512, 256, 0, stream>>>(WK, tq, KQ2);
    bias_fold<<<32, 256, 0, stream>>>(eb2, keyM, bK);
    bias_fold<<<32, 256, 0, stream>>>(eb2, valM, b2V);
    cb_kernel<<<200, 256, 0, stream>>>(bK, tq, cb);

    // ---- 3) backbone ----
    gemm_pair<0, true, false><<<dim3(64, 4, 1), 512, LDS_PAIR, stream>>>(
        obs_h, obs_l, 128, 0, bW1t_h, bW1t_l, 128, 0, bb1, 0,
        t1_h, t1_l, nullptr, 512, 0, 128, nullptr, nullptr, nullptr, nullptr);
    gemm_pair<0, true, false><<<dim3(64, 4, 1), 512, LDS_PAIR, stream>>>(
        t1_h, t1_l, 512, 0, bW2t_h, bW2t_l, 512, 0, bb2, 0,
        h2_h, h2_l, nullptr, 512, 0, 512, nullptr, nullptr, nullptr, nullptr);

    // ---- 4) pass A: one flat M=8192 x N=8192 GEMM; scores + U ----
    scores_init<<<512, 256, 0, stream>>>(task, cb, scores);
    gemm_pair<5, true, false><<<dim3(64, 64, 1), 512, LDS_PAIR, stream>>>(
        h2_h, h2_l, 512, 0, eW1t_h, eW1t_l, 512, 0, eb1, 0,
        U, nullptr, nullptr, 8192, 0, 512, nullptr, task, KQ2, scores);
    softmax16<<<32, 256, 0, stream>>>(scores);

    // ---- 5) tower: towerAcc = wb + (w .* U) @ Wv2 (scale fused in staging) --
    wb_init<<<8192, 256, 0, stream>>>(scores, b2V, towerAcc);
    gemm_pair<3, false, true><<<dim3(64, 4, 1), 512, LDS_PAIR, stream>>>(
        U, nullptr, 8192, 0, Wv2_h, Wv2_l, 8192, 0, nullptr, 0,
        nullptr, nullptr, towerAcc, 512, 0, 8192, scores, nullptr, nullptr, nullptr);

    // ---- 6) heads: layer-1 into Rcat [8192][1024] (z=2), fused GEMV+squash --
    split_pairs<<<4096, 256, 0, stream>>>(towerAcc, twP_h, twP_l, 1048576);
    gemm_pair<0, true, false><<<dim3(64, 4, 2), 512, LDS_PAIR, stream>>>(
        twP_h, twP_l, 512, 0, mW1t_h, mW1t_l, 512, 262144, bcat, 512,
        Rcat_h, Rcat_l, nullptr, 1024, 512, 512, nullptr, nullptr, nullptr, nullptr);
    head_kernel2<<<2048, 256, 0, stream>>>(Rcat_h, Rcat_l, W2T, mb2, lb2, eps,
                                           (float*)d_out, (float*)d_out + 262144);
}

// Round 6
// 758.122 us; speedup vs baseline: 1.3305x; 1.3305x over previous
//
#include <hip/hip_runtime.h>
#include <hip/hip_bf16.h>
#include <cstdint>

// ---------------------------------------------------------------------------
// SquashedGaussianMoEActor forward, MI355X (gfx950).
// Split-f16 MFMA (hi/lo pairs, 3x v_mfma_f32_16x16x32_f16) = fp32-quality.
// Attention folded: score = t1.(eW2@K@q), vals = t1@(eW2@V); eo never built.
// R6: R4-proven GEMM structure (64x128, 256thr, 3 blk/CU); mixture fuses
// softmax scaling into reg-staged A; KQ2 via two tiny GEMMs (keyM@tq^T then
// eW2@Kq^T) replacing keyM-transpose + WK-fold + kq_kernel + bK/cb kernels.
// B=8192, OBS=128, H=D=512, E=16, T=50, A=32.
// ---------------------------------------------------------------------------

typedef _Float16 f16;
typedef _Float16 f16x4 __attribute__((ext_vector_type(4)));
typedef _Float16 f16x8 __attribute__((ext_vector_type(8)));
typedef float f32x4 __attribute__((ext_vector_type(4)));

__device__ __forceinline__ void fsplit(float x, f16& h, f16& l) {
    h = (f16)x;
    l = (f16)(x - (float)h);
}

__device__ __forceinline__ void gload16(const void* g, void* s) {
    __builtin_amdgcn_global_load_lds(
        (const __attribute__((address_space(1))) void*)g,
        (__attribute__((address_space(3))) void*)s, 16, 0, 0);
}

// --- elementwise fp32 -> f16 pair split -----------------------------------
__global__ void split_pairs(const float* __restrict__ x, f16* __restrict__ h,
                            f16* __restrict__ l, int n4) {
    int i = blockIdx.x * 256 + threadIdx.x;
    if (i >= n4) return;
    float4 v = ((const float4*)x)[i];
    float a[4] = {v.x, v.y, v.z, v.w};
    f16x4 hh, ll;
#pragma unroll
    for (int j = 0; j < 4; ++j) { f16 hj, lj; fsplit(a[j], hj, lj); hh[j] = hj; ll[j] = lj; }
    *(f16x4*)&h[(long)i * 4] = hh;
    *(f16x4*)&l[(long)i * 4] = ll;
}

// --- transpose [K,N] fp32 -> [N,K] f16 pairs (batched via z) ---------------
__global__ void transpose_split(const float* __restrict__ W, f16* __restrict__ Th,
                                f16* __restrict__ Tl, int K, int N, long ist, long ost) {
    __shared__ float t[32][33];
    const float* Wb = W + (long)blockIdx.z * ist;
    const int k0 = blockIdx.x * 32, n0 = blockIdx.y * 32;
    const int tid = threadIdx.x;
    const int r = tid >> 3, c4 = (tid & 7) * 4;
    float4 v = *(const float4*)&Wb[(long)(k0 + r) * N + n0 + c4];
    t[r][c4] = v.x; t[r][c4 + 1] = v.y; t[r][c4 + 2] = v.z; t[r][c4 + 3] = v.w;
    __syncthreads();
    f16x4 hh, ll;
#pragma unroll
    for (int j = 0; j < 4; ++j) { f16 hj, lj; fsplit(t[c4 + j][r], hj, lj); hh[j] = hj; ll[j] = lj; }
    long ob = (long)blockIdx.z * ost + (long)(n0 + r) * K + k0 + c4;
    *(f16x4*)&Th[ob] = hh;
    *(f16x4*)&Tl[ob] = ll;
}

// --- W2T[half][col][k]: [0]=mW2^T, [1]=lW2^T (f32) -------------------------
__global__ void build_w2t(const float* __restrict__ mW2, const float* __restrict__ lW2,
                          float* __restrict__ W2T) {
    const int i = blockIdx.x * 256 + threadIdx.x;  // 32768
    const int half = i >> 14, col = (i >> 9) & 31, k = i & 511;
    const float* src = half ? lW2 : mW2;
    W2T[i] = src[k * 32 + col];
}

// --- bcat = [mb1 ; lb1] ----------------------------------------------------
__global__ void build_bcat(const float* __restrict__ mb1, const float* __restrict__ lb1,
                           float* __restrict__ bcat) {
    const int i = blockIdx.x * 256 + threadIdx.x;  // 1024
    bcat[i] = (i < 512) ? mb1[i] : lb1[i - 512];
}

// --- split-f16 GEMM: C = act(A @ B^T_stored + bias) ------------------------
// Tile 64x128, BK=64, 4 waves each owning 32x64 (2x4 frags of 16x16x32).
// Staging via global_load_lds (linear LDS dest, pre-swizzled global source;
// read side applies the same chunk^=row&7 involution). Single-buffered,
// 3 blocks/CU (4 for ASINGLE) -- inter-block overlap hides barrier drains.
// OUTM: 0 pair write, 1 pair write transposed, 2 f32 write, 3 f32 accum,
//       5 score mode (flat expert=col0>>9; row-dot KQ2 -> atomicAdd) + write
//         t1 single-f16 to Ch (U buffer), 6 f32 write transposed.
// ASINGLE: A single plane, reg-staged with fused per-(row, ktile) wscale.
template <int OUTM, bool RELU, bool ASINGLE>
__global__ __launch_bounds__(256, ASINGLE ? 4 : 3) void gemm_pair(
    const f16* __restrict__ Ah, const f16* __restrict__ Al, int lda, long zsA,
    const f16* __restrict__ Bh, const f16* __restrict__ Bl, int ldb, long zsB,
    const float* __restrict__ bias, long zsBias,
    f16* __restrict__ Ch, f16* __restrict__ Cl, float* __restrict__ Cf,
    int ldc, long zsC, int K,
    const float* __restrict__ wscale,
    const int* __restrict__ task, const float* __restrict__ KQ2,
    float* __restrict__ scores) {
    __shared__ f16 As[ASINGLE ? 1 : 2][64][64];
    __shared__ f16 Bs[2][128][64];
    const int z = blockIdx.z;
    Ah += (long)z * zsA;
    if constexpr (!ASINGLE) Al += (long)z * zsA;
    Bh += (long)z * zsB; Bl += (long)z * zsB;
    if (bias) bias += (long)z * zsBias;
    if (OUTM <= 1) { Ch += (long)z * zsC; Cl += (long)z * zsC; }
    if (OUTM == 2 || OUTM == 3 || OUTM == 6) { Cf += (long)z * zsC; }
    const int tid = threadIdx.x;
    const int l = tid & 63;
    const int w = tid >> 6;
    const int row0 = blockIdx.x * 64;
    const int col0 = blockIdx.y * 128;
    const int wr = (w >> 1) * 32;
    const int wc = (w & 1) * 64;
    const int grow = l >> 3;           // row within 8-row group
    const int gch = (l & 7) ^ grow;    // pre-swizzled k-chunk for gload_lds

    f32x4 acc[2][4];
#pragma unroll
    for (int mi = 0; mi < 2; ++mi)
#pragma unroll
        for (int ni = 0; ni < 4; ++ni)
#pragma unroll
            for (int j = 0; j < 4; ++j) acc[mi][ni][j] = 0.f;

    // ASINGLE: reg-staged A with fused per-(row, ktile) scale
    uint4 areg0, areg1; float ascl0, ascl1;
    auto ldA = [&](int k0) {
        const int r0 = w * 16 + grow, r1 = r0 + 8;
        const int scl = l & 7;
        areg0 = *(const uint4*)&Ah[(long)(row0 + r0) * lda + k0 + scl * 8];
        areg1 = *(const uint4*)&Ah[(long)(row0 + r1) * lda + k0 + scl * 8];
        const int e = k0 >> 9;
        ascl0 = wscale[(long)(row0 + r0) * 16 + e];
        ascl1 = wscale[(long)(row0 + r1) * 16 + e];
    };
    auto wrA = [&]() {
        const int scl = l & 7;
#pragma unroll
        for (int h = 0; h < 2; ++h) {
            const int r = w * 16 + grow + h * 8;
            const float s = h ? ascl1 : ascl0;
            f16x8 v = h ? *(f16x8*)&areg1 : *(f16x8*)&areg0;
#pragma unroll
            for (int j = 0; j < 8; ++j) v[j] = (f16)((float)v[j] * s);
            *(uint4*)&As[0][r][(scl ^ (r & 7)) * 8] = *(uint4*)&v;
        }
    };

    if constexpr (ASINGLE) ldA(0);
    for (int k0 = 0; k0 < K; k0 += 64) {
        __syncthreads();
        if constexpr (ASINGLE) {
            wrA();
            if (k0 + 64 < K) ldA(k0 + 64);  // issue next loads early (hidden under compute)
        } else {
            // A: wave w stages rows [w*16, w*16+16), both planes
            const long ga = (long)(row0 + w * 16 + grow) * lda + k0 + gch * 8;
            gload16(Ah + ga, &As[0][w * 16][0]);
            gload16(Ah + ga + (long)8 * lda, &As[0][w * 16 + 8][0]);
            gload16(Al + ga, &As[1][w * 16][0]);
            gload16(Al + ga + (long)8 * lda, &As[1][w * 16 + 8][0]);
        }
        {
            // B: wave w stages rows [w*32, w*32+32), both planes
            const long gb = (long)(col0 + w * 32 + grow) * ldb + k0 + gch * 8;
            gload16(Bh + gb, &Bs[0][w * 32][0]);
            gload16(Bh + gb + (long)8 * ldb, &Bs[0][w * 32 + 8][0]);
            gload16(Bh + gb + (long)16 * ldb, &Bs[0][w * 32 + 16][0]);
            gload16(Bh + gb + (long)24 * ldb, &Bs[0][w * 32 + 24][0]);
            gload16(Bl + gb, &Bs[1][w * 32][0]);
            gload16(Bl + gb + (long)8 * ldb, &Bs[1][w * 32 + 8][0]);
            gload16(Bl + gb + (long)16 * ldb, &Bs[1][w * 32 + 16][0]);
            gload16(Bl + gb + (long)24 * ldb, &Bs[1][w * 32 + 24][0]);
        }
        __syncthreads();
        const int r16 = l & 15, kg = l >> 4;
#pragma unroll
        for (int ks = 0; ks < 2; ++ks) {
            f16x8 a_h[2], a_l[2], b_h[4], b_l[4];
#pragma unroll
            for (int mi = 0; mi < 2; ++mi) {
                const int r = wr + mi * 16 + r16;
                const int off = ((ks * 4 + kg) ^ (r & 7)) * 8;
                a_h[mi] = *(const f16x8*)&As[0][r][off];
                if constexpr (!ASINGLE) a_l[mi] = *(const f16x8*)&As[1][r][off];
            }
#pragma unroll
            for (int ni = 0; ni < 4; ++ni) {
                const int c = wc + ni * 16 + r16;
                const int off = ((ks * 4 + kg) ^ (c & 7)) * 8;
                b_h[ni] = *(const f16x8*)&Bs[0][c][off];
                b_l[ni] = *(const f16x8*)&Bs[1][c][off];
            }
#pragma unroll
            for (int mi = 0; mi < 2; ++mi)
#pragma unroll
                for (int ni = 0; ni < 4; ++ni) {
                    acc[mi][ni] = __builtin_amdgcn_mfma_f32_16x16x32_f16(a_h[mi], b_h[ni], acc[mi][ni], 0, 0, 0);
                    acc[mi][ni] = __builtin_amdgcn_mfma_f32_16x16x32_f16(a_h[mi], b_l[ni], acc[mi][ni], 0, 0, 0);
                    if constexpr (!ASINGLE)
                        acc[mi][ni] = __builtin_amdgcn_mfma_f32_16x16x32_f16(a_l[mi], b_h[ni], acc[mi][ni], 0, 0, 0);
                }
        }
    }
    // epilogue. C layout (m89-verified): col = lane&15, row = (lane>>4)*4 + reg.
    const int lane15 = l & 15;
    const int rsub = (l >> 4) * 4;
    if (OUTM == 5) {
        const int expert = col0 >> 9;
        float bv[4];
#pragma unroll
        for (int ni = 0; ni < 4; ++ni)
            bv[ni] = bias ? bias[col0 + wc + ni * 16 + lane15] : 0.f;
#pragma unroll
        for (int mi = 0; mi < 2; ++mi)
#pragma unroll
            for (int j = 0; j < 4; ++j) {
                const int rowg = row0 + wr + mi * 16 + rsub + j;
                const int t = task[rowg];
                const float* kqr = KQ2 + ((long)t * 16 + expert) * 512;
                float part = 0.f;
#pragma unroll
                for (int ni = 0; ni < 4; ++ni) {
                    const int colg = col0 + wc + ni * 16 + lane15;
                    float v = acc[mi][ni][j] + bv[ni];
                    if (RELU) v = fmaxf(v, 0.f);
                    Ch[(long)rowg * ldc + colg] = (f16)v;
                    part += v * kqr[colg & 511];
                }
#pragma unroll
                for (int d = 1; d < 16; d <<= 1) part += __shfl_xor(part, d);
                if (lane15 == 0) atomicAdd(&scores[rowg * 16 + expert], part);
            }
    } else {
#pragma unroll
        for (int mi = 0; mi < 2; ++mi)
#pragma unroll
            for (int ni = 0; ni < 4; ++ni) {
                const int colg = col0 + wc + ni * 16 + lane15;
                const float bv = bias ? bias[colg] : 0.f;
#pragma unroll
                for (int j = 0; j < 4; ++j) {
                    const int rowg = row0 + wr + mi * 16 + rsub + j;
                    float v = acc[mi][ni][j] + bv;
                    if (RELU) v = fmaxf(v, 0.f);
                    if (OUTM == 0) {
                        f16 hh, ll; fsplit(v, hh, ll);
                        const long idx = (long)rowg * ldc + colg;
                        Ch[idx] = hh; Cl[idx] = ll;
                    } else if (OUTM == 1) {
                        f16 hh, ll; fsplit(v, hh, ll);
                        const long idx = (long)colg * ldc + rowg;
                        Ch[idx] = hh; Cl[idx] = ll;
                    } else if (OUTM == 2) {
                        Cf[(long)rowg * ldc + colg] = v;
                    } else if (OUTM == 3) {
                        Cf[(long)rowg * ldc + colg] += v;
                    } else if (OUTM == 6) {
                        Cf[(long)colg * ldc + rowg] = v;
                    }
                }
            }
    }
}

// --- cb[t][e] = sum_k eb2[e,k] * Kq[e,k,t]  (from KqT pairs) ---------------
__global__ void cb_from_kq(const f16* __restrict__ KqT_h, const f16* __restrict__ KqT_l,
                           const float* __restrict__ eb2, float* __restrict__ cb) {
    const int gw = (blockIdx.x * 256 + threadIdx.x) >> 6;  // 0..799
    const int l = threadIdx.x & 63;
    const int t = gw >> 4, e = gw & 15;
    const long base = (long)t * 8192 + e * 512 + l * 8;
    f16x8 hh = *(const f16x8*)&KqT_h[base];
    f16x8 ll = *(const f16x8*)&KqT_l[base];
    const float* bb = eb2 + e * 512 + l * 8;
    float s = 0.f;
#pragma unroll
    for (int j = 0; j < 8; ++j) s += ((float)hh[j] + (float)ll[j]) * bb[j];
#pragma unroll
    for (int d = 1; d < 64; d <<= 1) s += __shfl_xor(s, d);
    if (l == 0) cb[t * 16 + e] = s;
}

// --- out[e*512+j] = sum_k bvec[e*512+k] * M[e][k][j] -----------------------
__global__ void bias_fold(const float* __restrict__ bvec, const float* __restrict__ M,
                          float* __restrict__ out) {
    const int gid = blockIdx.x * 256 + threadIdx.x;  // 8192
    const int e = gid >> 9, j = gid & 511;
    const float* Me = M + (long)e * 262144;
    const float* be = bvec + e * 512;
    float s = 0.f;
    for (int k = 0; k < 512; ++k) s += be[k] * Me[(long)k * 512 + j];
    out[gid] = s;
}

// --- scores[b*16+e] = cb[task[b]*16+e] -------------------------------------
__global__ void scores_init(const int* __restrict__ task, const float* __restrict__ cb,
                            float* __restrict__ sc) {
    const int i = blockIdx.x * 256 + threadIdx.x;  // 131072
    sc[i] = cb[task[i >> 4] * 16 + (i & 15)];
}

// --- in-place softmax over E=16 per row ------------------------------------
__global__ void softmax16(float* __restrict__ sc) {
    const int b = blockIdx.x * 256 + threadIdx.x;  // 8192
    float v[16];
    const float4* pp = (const float4*)&sc[b * 16];
#pragma unroll
    for (int qq = 0; qq < 4; ++qq) {
        float4 t = pp[qq];
        v[qq * 4] = t.x; v[qq * 4 + 1] = t.y; v[qq * 4 + 2] = t.z; v[qq * 4 + 3] = t.w;
    }
    float m = v[0];
#pragma unroll
    for (int e = 1; e < 16; ++e) m = fmaxf(m, v[e]);
    float ssum = 0.f;
#pragma unroll
    for (int e = 0; e < 16; ++e) { v[e] = expf(v[e] - m); ssum += v[e]; }
    const float inv = 1.f / ssum;
    float4* o = (float4*)&sc[b * 16];
#pragma unroll
    for (int qq = 0; qq < 4; ++qq) {
        float4 t;
        t.x = v[qq * 4] * inv; t.y = v[qq * 4 + 1] * inv;
        t.z = v[qq * 4 + 2] * inv; t.w = v[qq * 4 + 3] * inv;
        o[qq] = t;
    }
}

// --- towerAcc[b][j] = sum_e w[b][e] * b2V[e][j] ----------------------------
__global__ void wb_init(const float* __restrict__ w, const float* __restrict__ b2V,
                        float* __restrict__ towerAcc) {
    const int b = blockIdx.x;
    const int tid = threadIdx.x;
    float wv[16];
#pragma unroll
    for (int e = 0; e < 16; ++e) wv[e] = w[b * 16 + e];
#pragma unroll
    for (int rep = 0; rep < 2; ++rep) {
        const int j = rep * 256 + tid;
        float s = 0.f;
#pragma unroll
        for (int e = 0; e < 16; ++e) s += wv[e] * b2V[e * 512 + j];
        towerAcc[(long)b * 512 + j] = s;
    }
}

// --- final heads: GEMV vs W2T (float4 streams), squash, logp ---------------
__global__ void head_kernel2(
    const f16* __restrict__ Rh, const f16* __restrict__ Rl,
    const float* __restrict__ W2T,   // [2][32][512]
    const float* __restrict__ mb2, const float* __restrict__ lb2,
    const float* __restrict__ eps, float* __restrict__ pi, float* __restrict__ logp) {
    __shared__ float src[4][1032];
    const int tid = threadIdx.x, l = tid & 63, w = tid >> 6;
    const int b = blockIdx.x * 4 + w;  // one wave per row
    const long rb = (long)b * 1024;
    {
        f16x8 h0 = *(const f16x8*)&Rh[rb + l * 8];
        f16x8 l0 = *(const f16x8*)&Rl[rb + l * 8];
        f16x8 h1 = *(const f16x8*)&Rh[rb + 512 + l * 8];
        f16x8 l1 = *(const f16x8*)&Rl[rb + 512 + l * 8];
#pragma unroll
        for (int j = 0; j < 8; ++j) {
            src[w][l * 8 + j] = (float)h0[j] + (float)l0[j];
            src[w][512 + l * 8 + j] = (float)h1[j] + (float)l1[j];
        }
    }
    __syncthreads();
    const int col = l & 31;
    const int half = l >> 5;  // 0 = mu, 1 = log_std
    const float4* wp = (const float4*)(W2T + ((long)(half * 32 + col)) * 512);
    const float4* sp = (const float4*)(&src[w][half * 512]);
    float a0 = 0.f, a1 = 0.f, a2 = 0.f, a3 = 0.f;
#pragma unroll 8
    for (int k4 = 0; k4 < 128; ++k4) {
        const float4 wv = wp[k4];
        const float4 sv = sp[k4];
        a0 = fmaf(wv.x, sv.x, a0);
        a1 = fmaf(wv.y, sv.y, a1);
        a2 = fmaf(wv.z, sv.z, a2);
        a3 = fmaf(wv.w, sv.w, a3);
    }
    const float* b2 = half ? lb2 : mb2;
    float s = b2[col] + ((a0 + a1) + (a2 + a3));
    const float other = __shfl_xor(s, 32);  // swap mu <-> log_std halves
    if (half == 0) {
        const float mu = s;
        float ls = fminf(fmaxf(other, -20.f), 2.f);
        const float e = eps[(long)b * 32 + col];
        const float a = mu + expf(ls) * e;
        float lt = -0.5f * e * e - ls - 0.91893853320467274f;  // -0.5*log(2*pi)
        const float x = -2.f * a;
        const float sp2 = fmaxf(x, 0.f) + log1pf(expf(-fabsf(x)));
        lt -= 2.f * (0.69314718055994531f - a - sp2);
        pi[(long)b * 32 + col] = tanhf(a);
        float r = lt;
#pragma unroll
        for (int d = 1; d < 32; d <<= 1) r += __shfl_xor(r, d);
        if (col == 0) logp[b] = r;
    }
}

// ---------------------------------------------------------------------------
extern "C" void kernel_launch(void* const* d_in, const int* in_sizes, int n_in,
                              void* d_out, int out_size, void* d_ws, size_t ws_size,
                              hipStream_t stream) {
    const float* obs = (const float*)d_in[0];
    const int* task = (const int*)d_in[1];
    const float* eps = (const float*)d_in[2];
    const float* bW1 = (const float*)d_in[3];
    const float* bb1 = (const float*)d_in[4];
    const float* bW2 = (const float*)d_in[5];
    const float* bb2 = (const float*)d_in[6];
    const float* eW1 = (const float*)d_in[7];
    const float* eb1 = (const float*)d_in[8];
    const float* eW2 = (const float*)d_in[9];
    const float* eb2 = (const float*)d_in[10];
    const float* keyM = (const float*)d_in[11];
    const float* valM = (const float*)d_in[12];
    const float* tq = (const float*)d_in[13];
    const float* mW1 = (const float*)d_in[14];
    const float* mb1 = (const float*)d_in[15];
    const float* mW2 = (const float*)d_in[16];
    const float* mb2 = (const float*)d_in[17];
    const float* lW1 = (const float*)d_in[18];
    const float* lb1 = (const float*)d_in[19];
    const float* lW2 = (const float*)d_in[20];
    const float* lb2 = (const float*)d_in[21];
    (void)in_sizes; (void)n_in; (void)out_size; (void)ws_size;

    // ---- workspace map (base 122 MB + 128 MB U; ws >= 251 MB verified R4) --
    const size_t MB = 1u << 20, KB = 1u << 10;
    char* base = (char*)d_ws;
    f16* eW1t_h = (f16*)(base + 0 * MB);   f16* eW1t_l = (f16*)(base + 8 * MB);
    f16* Wv2_h  = (f16*)(base + 16 * MB);  f16* Wv2_l  = (f16*)(base + 24 * MB);  // [j2][(e,i)]
    f16* eW2s_h = (f16*)(base + 32 * MB);  f16* eW2s_l = (f16*)(base + 40 * MB);
    f16* h2_h   = (f16*)(base + 32 * MB);  f16* h2_l   = (f16*)(base + 40 * MB);  // after folds
    f16* t1_h   = (f16*)(base + 48 * MB);  f16* t1_l   = (f16*)(base + 56 * MB);
    f16* Rcat_l = (f16*)(base + 48 * MB);                                         // heads (t1 dead)
    f16* Vt_h   = (f16*)(base + 64 * MB);  f16* Vt_l   = (f16*)(base + 72 * MB);
    f16* Rcat_h = (f16*)(base + 64 * MB);                                         // heads (Vt dead)
    // 80-112 MB region, phase 1 (KQ path): keyM pairs, KqT, tqP, KQ2
    f16* keyMs_h = (f16*)(base + 80 * MB); f16* keyMs_l = (f16*)(base + 88 * MB);
    f16* KqT_h   = (f16*)(base + 96 * MB); f16* KqT_l   = (f16*)(base + 98 * MB); // [128][8192]
    f16* tqP_h   = (f16*)(base + 100 * MB); f16* tqP_l  = (f16*)(base + 101 * MB); // [128][512]
    float* KQ2   = (float*)(base + 104 * MB);                                     // [128][16][512] f32
    // 80-112 MB region, phase 2 (tower/heads): towerAcc, twP
    float* towerAcc = (float*)(base + 80 * MB);                                   // 16 MB
    f16* twP_h  = (f16*)(base + 96 * MB);  f16* twP_l  = (f16*)(base + 104 * MB);
    f16* obs_h  = (f16*)(base + 112 * MB); f16* obs_l  = (f16*)(base + 114 * MB);
    char* q = base + 116 * MB;
    f16* bW1t_h = (f16*)q; q += 128 * KB;  f16* bW1t_l = (f16*)q; q += 128 * KB;
    f16* bW2t_h = (f16*)q; q += 512 * KB;  f16* bW2t_l = (f16*)q; q += 512 * KB;
    // order m_h, l_h, m_l, l_l so the z=2 head GEMM can stride (zsB = 262144)
    f16* mW1t_h = (f16*)q; q += 512 * KB;
    f16* lW1t_h = (f16*)q; q += 512 * KB;
    f16* mW1t_l = (f16*)q; q += 512 * KB;
    f16* lW1t_l = (f16*)q; q += 512 * KB;
    float* scores = (float*)q; q += 512 * KB;    // 8192*16 f32 (becomes w)
    float* b2V    = (float*)q; q += 32 * KB;
    float* cb     = (float*)q; q += 16 * KB;
    float* W2T    = (float*)q; q += 128 * KB;    // [2][32][512]
    float* bcat   = (float*)q; q += 16 * KB;     // [2][512]
    f16* U = (f16*)(base + 122 * MB);            // [8192][8192] single f16

    const long EST = 262144;  // per-expert 512x512 stride

    // ---- 1) splits / transposes ----
    split_pairs<<<1024, 256, 0, stream>>>(obs, obs_h, obs_l, 262144);
    split_pairs<<<4096, 256, 0, stream>>>(eW2, eW2s_h, eW2s_l, 1048576);
    split_pairs<<<4096, 256, 0, stream>>>(keyM, keyMs_h, keyMs_l, 1048576);
    hipMemsetAsync(tqP_h, 0, 128 * 512 * sizeof(f16), stream);
    hipMemsetAsync(tqP_l, 0, 128 * 512 * sizeof(f16), stream);
    split_pairs<<<25, 256, 0, stream>>>(tq, tqP_h, tqP_l, 6400);
    transpose_split<<<dim3(4, 16, 1), 256, 0, stream>>>(bW1, bW1t_h, bW1t_l, 128, 512, 0, 0);
    transpose_split<<<dim3(16, 16, 1), 256, 0, stream>>>(bW2, bW2t_h, bW2t_l, 512, 512, 0, 0);
    transpose_split<<<dim3(16, 16, 1), 256, 0, stream>>>(mW1, mW1t_h, mW1t_l, 512, 512, 0, 0);
    transpose_split<<<dim3(16, 16, 1), 256, 0, stream>>>(lW1, lW1t_h, lW1t_l, 512, 512, 0, 0);
    transpose_split<<<dim3(16, 16, 16), 256, 0, stream>>>(eW1, eW1t_h, eW1t_l, 512, 512, EST, EST);
    transpose_split<<<dim3(16, 16, 16), 256, 0, stream>>>(valM, Vt_h, Vt_l, 512, 512, EST, EST);
    build_w2t<<<128, 256, 0, stream>>>(mW2, lW2, W2T);
    build_bcat<<<4, 256, 0, stream>>>(mb1, lb1, bcat);

    // ---- 2) attention folds ----
    // Wv2[j2][(e,i)] = (eW2@V)[i][j2]  (pair transposed write, ldc=8192, zsC=512)
    gemm_pair<1, false, false><<<dim3(8, 4, 16), 256, 0, stream>>>(
        eW2s_h, eW2s_l, 512, EST, Vt_h, Vt_l, 512, EST, nullptr, 0,
        Wv2_h, Wv2_l, nullptr, 8192, 512, 512, nullptr, nullptr, nullptr, nullptr);
    // KqT[t][(e,k)] = (keyM @ tq^T)[(e,k)][t]   (N=128 padded, pair transposed)
    gemm_pair<1, false, false><<<dim3(128, 1, 1), 256, 0, stream>>>(
        keyMs_h, keyMs_l, 512, 0, tqP_h, tqP_l, 512, 0, nullptr, 0,
        KqT_h, KqT_l, nullptr, 8192, 0, 512, nullptr, nullptr, nullptr, nullptr);
    // KQ2[(t,e)][i] = (eW2_e @ KqT_e^T)[i][t]   (f32 transposed write)
    gemm_pair<6, false, false><<<dim3(8, 1, 16), 256, 0, stream>>>(
        eW2s_h, eW2s_l, 512, EST, KqT_h, KqT_l, 8192, 512, nullptr, 0,
        nullptr, nullptr, KQ2, 8192, 512, 512, nullptr, nullptr, nullptr, nullptr);
    cb_from_kq<<<200, 256, 0, stream>>>(KqT_h, KqT_l, eb2, cb);
    bias_fold<<<32, 256, 0, stream>>>(eb2, valM, b2V);

    // ---- 3) backbone ----
    gemm_pair<0, true, false><<<dim3(128, 4, 1), 256, 0, stream>>>(
        obs_h, obs_l, 128, 0, bW1t_h, bW1t_l, 128, 0, bb1, 0,
        t1_h, t1_l, nullptr, 512, 0, 128, nullptr, nullptr, nullptr, nullptr);
    gemm_pair<0, true, false><<<dim3(128, 4, 1), 256, 0, stream>>>(
        t1_h, t1_l, 512, 0, bW2t_h, bW2t_l, 512, 0, bb2, 0,
        h2_h, h2_l, nullptr, 512, 0, 512, nullptr, nullptr, nullptr, nullptr);

    // ---- 4) pass A: one flat M=8192 x N=8192 GEMM; scores + U ----
    scores_init<<<512, 256, 0, stream>>>(task, cb, scores);
    gemm_pair<5, true, false><<<dim3(128, 64, 1), 256, 0, stream>>>(
        h2_h, h2_l, 512, 0, eW1t_h, eW1t_l, 512, 0, eb1, 0,
        U, nullptr, nullptr, 8192, 0, 512, nullptr, task, KQ2, scores);
    softmax16<<<32, 256, 0, stream>>>(scores);

    // ---- 5) tower: towerAcc = wb + (w .* U) @ Wv2 (scale fused in staging) --
    wb_init<<<8192, 256, 0, stream>>>(scores, b2V, towerAcc);
    gemm_pair<3, false, true><<<dim3(128, 4, 1), 256, 0, stream>>>(
        U, nullptr, 8192, 0, Wv2_h, Wv2_l, 8192, 0, nullptr, 0,
        nullptr, nullptr, towerAcc, 512, 0, 8192, scores, nullptr, nullptr, nullptr);

    // ---- 6) heads: layer-1 into Rcat [8192][1024] (z=2), fused GEMV+squash --
    split_pairs<<<4096, 256, 0, stream>>>(towerAcc, twP_h, twP_l, 1048576);
    gemm_pair<0, true, false><<<dim3(128, 4, 2), 256, 0, stream>>>(
        twP_h, twP_l, 512, 0, mW1t_h, mW1t_l, 512, 262144, bcat, 512,
        Rcat_h, Rcat_l, nullptr, 1024, 512, 512, nullptr, nullptr, nullptr, nullptr);
    head_kernel2<<<2048, 256, 0, stream>>>(Rcat_h, Rcat_l, W2T, mb2, lb2, eps,
                                           (float*)d_out, (float*)d_out + 262144);
}

// Round 7
// 705.373 us; speedup vs baseline: 1.4300x; 1.0748x over previous
//
#include <hip/hip_runtime.h>
#include <hip/hip_bf16.h>
#include <cstdint>

// ---------------------------------------------------------------------------
// SquashedGaussianMoEActor forward, MI355X (gfx950).
// Split-f16 MFMA (hi/lo pairs, 3x v_mfma_f32_16x16x32_f16) = fp32-quality
// where it matters (scores); single-f16 on the tower path (error budget
// verified empirically: absmax 4.0 / threshold 14.56 at R6).
// R7: mixture U@Wv2 as plain 1-MFMA GEMM (both single-f16), wb+pair-split
// fused into its epilogue; Wv2 fold writes single plane.
// B=8192, OBS=128, H=D=512, E=16, T=50, A=32.
// ---------------------------------------------------------------------------

typedef _Float16 f16;
typedef _Float16 f16x4 __attribute__((ext_vector_type(4)));
typedef _Float16 f16x8 __attribute__((ext_vector_type(8)));
typedef float f32x4 __attribute__((ext_vector_type(4)));

__device__ __forceinline__ void fsplit(float x, f16& h, f16& l) {
    h = (f16)x;
    l = (f16)(x - (float)h);
}

__device__ __forceinline__ void gload16(const void* g, void* s) {
    __builtin_amdgcn_global_load_lds(
        (const __attribute__((address_space(1))) void*)g,
        (__attribute__((address_space(3))) void*)s, 16, 0, 0);
}

// --- elementwise fp32 -> f16 pair split -----------------------------------
__global__ void split_pairs(const float* __restrict__ x, f16* __restrict__ h,
                            f16* __restrict__ l, int n4) {
    int i = blockIdx.x * 256 + threadIdx.x;
    if (i >= n4) return;
    float4 v = ((const float4*)x)[i];
    float a[4] = {v.x, v.y, v.z, v.w};
    f16x4 hh, ll;
#pragma unroll
    for (int j = 0; j < 4; ++j) { f16 hj, lj; fsplit(a[j], hj, lj); hh[j] = hj; ll[j] = lj; }
    *(f16x4*)&h[(long)i * 4] = hh;
    *(f16x4*)&l[(long)i * 4] = ll;
}

// --- transpose [K,N] fp32 -> [N,K] f16 pairs (batched via z) ---------------
__global__ void transpose_split(const float* __restrict__ W, f16* __restrict__ Th,
                                f16* __restrict__ Tl, int K, int N, long ist, long ost) {
    __shared__ float t[32][33];
    const float* Wb = W + (long)blockIdx.z * ist;
    const int k0 = blockIdx.x * 32, n0 = blockIdx.y * 32;
    const int tid = threadIdx.x;
    const int r = tid >> 3, c4 = (tid & 7) * 4;
    float4 v = *(const float4*)&Wb[(long)(k0 + r) * N + n0 + c4];
    t[r][c4] = v.x; t[r][c4 + 1] = v.y; t[r][c4 + 2] = v.z; t[r][c4 + 3] = v.w;
    __syncthreads();
    f16x4 hh, ll;
#pragma unroll
    for (int j = 0; j < 4; ++j) { f16 hj, lj; fsplit(t[c4 + j][r], hj, lj); hh[j] = hj; ll[j] = lj; }
    long ob = (long)blockIdx.z * ost + (long)(n0 + r) * K + k0 + c4;
    *(f16x4*)&Th[ob] = hh;
    *(f16x4*)&Tl[ob] = ll;
}

// --- W2T[half][col][k]: [0]=mW2^T, [1]=lW2^T (f32) -------------------------
__global__ void build_w2t(const float* __restrict__ mW2, const float* __restrict__ lW2,
                          float* __restrict__ W2T) {
    const int i = blockIdx.x * 256 + threadIdx.x;  // 32768
    const int half = i >> 14, col = (i >> 9) & 31, k = i & 511;
    const float* src = half ? lW2 : mW2;
    W2T[i] = src[k * 32 + col];
}

// --- bcat = [mb1 ; lb1] ----------------------------------------------------
__global__ void build_bcat(const float* __restrict__ mb1, const float* __restrict__ lb1,
                           float* __restrict__ bcat) {
    const int i = blockIdx.x * 256 + threadIdx.x;  // 1024
    bcat[i] = (i < 512) ? mb1[i] : lb1[i - 512];
}

// --- split-f16 GEMM: C = act(A @ B^T_stored + bias) ------------------------
// Tile 64x128, BK=64, 4 waves each owning 32x64 (2x4 frags of 16x16x32).
// Staging via global_load_lds (linear LDS dest, pre-swizzled global source;
// read side applies the same chunk^=row&7 involution). Single-buffered,
// 3+ blocks/CU -- inter-block overlap hides barrier drains (m114).
// OUTM: 0 pair write, 1 pair write transposed, 2 f32 write, 3 f32 accum,
//       5 score mode (flat expert=col0>>9; row-dot KQ2 -> atomicAdd) + write
//         t1 single-f16 to Ch (U buffer), 6 f32 write transposed,
//       7 single-f16 write transposed, 8 pair write with f32 C-input (Cf).
// ASINGLE: A single plane, reg-staged with fused per-(row, ktile) wscale.
// BSINGLE: B single plane (hi only).
template <int OUTM, bool RELU, bool ASINGLE, bool BSINGLE>
__global__ __launch_bounds__(256, ASINGLE ? 4 : 3) void gemm_pair(
    const f16* __restrict__ Ah, const f16* __restrict__ Al, int lda, long zsA,
    const f16* __restrict__ Bh, const f16* __restrict__ Bl, int ldb, long zsB,
    const float* __restrict__ bias, long zsBias,
    f16* __restrict__ Ch, f16* __restrict__ Cl, float* __restrict__ Cf,
    int ldc, long zsC, int K,
    const float* __restrict__ wscale,
    const int* __restrict__ task, const float* __restrict__ KQ2,
    float* __restrict__ scores) {
    __shared__ f16 As[ASINGLE ? 1 : 2][64][64];
    __shared__ f16 Bs[BSINGLE ? 1 : 2][128][64];
    const int z = blockIdx.z;
    Ah += (long)z * zsA;
    if constexpr (!ASINGLE) Al += (long)z * zsA;
    Bh += (long)z * zsB;
    if constexpr (!BSINGLE) Bl += (long)z * zsB;
    if (bias) bias += (long)z * zsBias;
    if (OUTM <= 1) { Ch += (long)z * zsC; Cl += (long)z * zsC; }
    if (OUTM == 7) { Ch += (long)z * zsC; }
    if (OUTM == 2 || OUTM == 3 || OUTM == 6) { Cf += (long)z * zsC; }
    const int tid = threadIdx.x;
    const int l = tid & 63;
    const int w = tid >> 6;
    const int row0 = blockIdx.x * 64;
    const int col0 = blockIdx.y * 128;
    const int wr = (w >> 1) * 32;
    const int wc = (w & 1) * 64;
    const int grow = l >> 3;           // row within 8-row group
    const int gch = (l & 7) ^ grow;    // pre-swizzled k-chunk for gload_lds

    f32x4 acc[2][4];
#pragma unroll
    for (int mi = 0; mi < 2; ++mi)
#pragma unroll
        for (int ni = 0; ni < 4; ++ni)
#pragma unroll
            for (int j = 0; j < 4; ++j) acc[mi][ni][j] = 0.f;

    // ASINGLE: reg-staged A with fused per-(row, ktile) scale
    uint4 areg0, areg1; float ascl0, ascl1;
    auto ldA = [&](int k0) {
        const int r0 = w * 16 + grow, r1 = r0 + 8;
        const int scl = l & 7;
        areg0 = *(const uint4*)&Ah[(long)(row0 + r0) * lda + k0 + scl * 8];
        areg1 = *(const uint4*)&Ah[(long)(row0 + r1) * lda + k0 + scl * 8];
        const int e = k0 >> 9;
        ascl0 = wscale[(long)(row0 + r0) * 16 + e];
        ascl1 = wscale[(long)(row0 + r1) * 16 + e];
    };
    auto wrA = [&]() {
        const int scl = l & 7;
#pragma unroll
        for (int h = 0; h < 2; ++h) {
            const int r = w * 16 + grow + h * 8;
            const float s = h ? ascl1 : ascl0;
            f16x8 v = h ? *(f16x8*)&areg1 : *(f16x8*)&areg0;
#pragma unroll
            for (int j = 0; j < 8; ++j) v[j] = (f16)((float)v[j] * s);
            *(uint4*)&As[0][r][(scl ^ (r & 7)) * 8] = *(uint4*)&v;
        }
    };

    if constexpr (ASINGLE) ldA(0);
    for (int k0 = 0; k0 < K; k0 += 64) {
        __syncthreads();
        if constexpr (ASINGLE) {
            wrA();
            if (k0 + 64 < K) ldA(k0 + 64);  // issue next loads early (hidden under compute)
        } else {
            // A: wave w stages rows [w*16, w*16+16), both planes
            const long ga = (long)(row0 + w * 16 + grow) * lda + k0 + gch * 8;
            gload16(Ah + ga, &As[0][w * 16][0]);
            gload16(Ah + ga + (long)8 * lda, &As[0][w * 16 + 8][0]);
            gload16(Al + ga, &As[1][w * 16][0]);
            gload16(Al + ga + (long)8 * lda, &As[1][w * 16 + 8][0]);
        }
        {
            // B: wave w stages rows [w*32, w*32+32)
            const long gb = (long)(col0 + w * 32 + grow) * ldb + k0 + gch * 8;
            gload16(Bh + gb, &Bs[0][w * 32][0]);
            gload16(Bh + gb + (long)8 * ldb, &Bs[0][w * 32 + 8][0]);
            gload16(Bh + gb + (long)16 * ldb, &Bs[0][w * 32 + 16][0]);
            gload16(Bh + gb + (long)24 * ldb, &Bs[0][w * 32 + 24][0]);
            if constexpr (!BSINGLE) {
                gload16(Bl + gb, &Bs[1][w * 32][0]);
                gload16(Bl + gb + (long)8 * ldb, &Bs[1][w * 32 + 8][0]);
                gload16(Bl + gb + (long)16 * ldb, &Bs[1][w * 32 + 16][0]);
                gload16(Bl + gb + (long)24 * ldb, &Bs[1][w * 32 + 24][0]);
            }
        }
        __syncthreads();
        const int r16 = l & 15, kg = l >> 4;
#pragma unroll
        for (int ks = 0; ks < 2; ++ks) {
            f16x8 a_h[2], a_l[2], b_h[4], b_l[4];
#pragma unroll
            for (int mi = 0; mi < 2; ++mi) {
                const int r = wr + mi * 16 + r16;
                const int off = ((ks * 4 + kg) ^ (r & 7)) * 8;
                a_h[mi] = *(const f16x8*)&As[0][r][off];
                if constexpr (!ASINGLE) a_l[mi] = *(const f16x8*)&As[1][r][off];
            }
#pragma unroll
            for (int ni = 0; ni < 4; ++ni) {
                const int c = wc + ni * 16 + r16;
                const int off = ((ks * 4 + kg) ^ (c & 7)) * 8;
                b_h[ni] = *(const f16x8*)&Bs[0][c][off];
                if constexpr (!BSINGLE) b_l[ni] = *(const f16x8*)&Bs[1][c][off];
            }
#pragma unroll
            for (int mi = 0; mi < 2; ++mi)
#pragma unroll
                for (int ni = 0; ni < 4; ++ni) {
                    acc[mi][ni] = __builtin_amdgcn_mfma_f32_16x16x32_f16(a_h[mi], b_h[ni], acc[mi][ni], 0, 0, 0);
                    if constexpr (!BSINGLE)
                        acc[mi][ni] = __builtin_amdgcn_mfma_f32_16x16x32_f16(a_h[mi], b_l[ni], acc[mi][ni], 0, 0, 0);
                    if constexpr (!ASINGLE)
                        acc[mi][ni] = __builtin_amdgcn_mfma_f32_16x16x32_f16(a_l[mi], b_h[ni], acc[mi][ni], 0, 0, 0);
                }
        }
    }
    // epilogue. C layout (m89-verified): col = lane&15, row = (lane>>4)*4 + reg.
    const int lane15 = l & 15;
    const int rsub = (l >> 4) * 4;
    if (OUTM == 5) {
        const int expert = col0 >> 9;
        float bv[4];
#pragma unroll
        for (int ni = 0; ni < 4; ++ni)
            bv[ni] = bias ? bias[col0 + wc + ni * 16 + lane15] : 0.f;
#pragma unroll
        for (int mi = 0; mi < 2; ++mi)
#pragma unroll
            for (int j = 0; j < 4; ++j) {
                const int rowg = row0 + wr + mi * 16 + rsub + j;
                const int t = task[rowg];
                const float* kqr = KQ2 + ((long)t * 16 + expert) * 512;
                float part = 0.f;
#pragma unroll
                for (int ni = 0; ni < 4; ++ni) {
                    const int colg = col0 + wc + ni * 16 + lane15;
                    float v = acc[mi][ni][j] + bv[ni];
                    if (RELU) v = fmaxf(v, 0.f);
                    Ch[(long)rowg * ldc + colg] = (f16)v;
                    part += v * kqr[colg & 511];
                }
#pragma unroll
                for (int d = 1; d < 16; d <<= 1) part += __shfl_xor(part, d);
                if (lane15 == 0) atomicAdd(&scores[rowg * 16 + expert], part);
            }
    } else {
#pragma unroll
        for (int mi = 0; mi < 2; ++mi)
#pragma unroll
            for (int ni = 0; ni < 4; ++ni) {
                const int colg = col0 + wc + ni * 16 + lane15;
                const float bv = bias ? bias[colg] : 0.f;
#pragma unroll
                for (int j = 0; j < 4; ++j) {
                    const int rowg = row0 + wr + mi * 16 + rsub + j;
                    float v = acc[mi][ni][j] + bv;
                    if (RELU) v = fmaxf(v, 0.f);
                    if (OUTM == 0) {
                        f16 hh, ll; fsplit(v, hh, ll);
                        const long idx = (long)rowg * ldc + colg;
                        Ch[idx] = hh; Cl[idx] = ll;
                    } else if (OUTM == 1) {
                        f16 hh, ll; fsplit(v, hh, ll);
                        const long idx = (long)colg * ldc + rowg;
                        Ch[idx] = hh; Cl[idx] = ll;
                    } else if (OUTM == 2) {
                        Cf[(long)rowg * ldc + colg] = v;
                    } else if (OUTM == 3) {
                        Cf[(long)rowg * ldc + colg] += v;
                    } else if (OUTM == 6) {
                        Cf[(long)colg * ldc + rowg] = v;
                    } else if (OUTM == 7) {
                        Ch[(long)colg * ldc + rowg] = (f16)v;
                    } else if (OUTM == 8) {
                        const long idx = (long)rowg * ldc + colg;
                        v += Cf[idx];   // wb input
                        f16 hh, ll; fsplit(v, hh, ll);
                        Ch[idx] = hh; Cl[idx] = ll;
                    }
                }
            }
    }
}

// --- cb[t][e] = sum_k eb2[e,k] * Kq[e,k,t]  (from KqT pairs) ---------------
__global__ void cb_from_kq(const f16* __restrict__ KqT_h, const f16* __restrict__ KqT_l,
                           const float* __restrict__ eb2, float* __restrict__ cb) {
    const int gw = (blockIdx.x * 256 + threadIdx.x) >> 6;  // 0..799
    const int l = threadIdx.x & 63;
    const int t = gw >> 4, e = gw & 15;
    const long base = (long)t * 8192 + e * 512 + l * 8;
    f16x8 hh = *(const f16x8*)&KqT_h[base];
    f16x8 ll = *(const f16x8*)&KqT_l[base];
    const float* bb = eb2 + e * 512 + l * 8;
    float s = 0.f;
#pragma unroll
    for (int j = 0; j < 8; ++j) s += ((float)hh[j] + (float)ll[j]) * bb[j];
#pragma unroll
    for (int d = 1; d < 64; d <<= 1) s += __shfl_xor(s, d);
    if (l == 0) cb[t * 16 + e] = s;
}

// --- out[e*512+j] = sum_k bvec[e*512+k] * M[e][k][j] -----------------------
__global__ void bias_fold(const float* __restrict__ bvec, const float* __restrict__ M,
                          float* __restrict__ out) {
    const int gid = blockIdx.x * 256 + threadIdx.x;  // 8192
    const int e = gid >> 9, j = gid & 511;
    const float* Me = M + (long)e * 262144;
    const float* be = bvec + e * 512;
    float s = 0.f;
    for (int k = 0; k < 512; ++k) s += be[k] * Me[(long)k * 512 + j];
    out[gid] = s;
}

// --- scores[b*16+e] = cb[task[b]*16+e] -------------------------------------
__global__ void scores_init(const int* __restrict__ task, const float* __restrict__ cb,
                            float* __restrict__ sc) {
    const int i = blockIdx.x * 256 + threadIdx.x;  // 131072
    sc[i] = cb[task[i >> 4] * 16 + (i & 15)];
}

// --- in-place softmax over E=16 per row ------------------------------------
__global__ void softmax16(float* __restrict__ sc) {
    const int b = blockIdx.x * 256 + threadIdx.x;  // 8192
    float v[16];
    const float4* pp = (const float4*)&sc[b * 16];
#pragma unroll
    for (int qq = 0; qq < 4; ++qq) {
        float4 t = pp[qq];
        v[qq * 4] = t.x; v[qq * 4 + 1] = t.y; v[qq * 4 + 2] = t.z; v[qq * 4 + 3] = t.w;
    }
    float m = v[0];
#pragma unroll
    for (int e = 1; e < 16; ++e) m = fmaxf(m, v[e]);
    float ssum = 0.f;
#pragma unroll
    for (int e = 0; e < 16; ++e) { v[e] = expf(v[e] - m); ssum += v[e]; }
    const float inv = 1.f / ssum;
    float4* o = (float4*)&sc[b * 16];
#pragma unroll
    for (int qq = 0; qq < 4; ++qq) {
        float4 t;
        t.x = v[qq * 4] * inv; t.y = v[qq * 4 + 1] * inv;
        t.z = v[qq * 4 + 2] * inv; t.w = v[qq * 4 + 3] * inv;
        o[qq] = t;
    }
}

// --- towerAcc[b][j] = sum_e w[b][e] * b2V[e][j] ----------------------------
__global__ void wb_init(const float* __restrict__ w, const float* __restrict__ b2V,
                        float* __restrict__ towerAcc) {
    const int b = blockIdx.x;
    const int tid = threadIdx.x;
    float wv[16];
#pragma unroll
    for (int e = 0; e < 16; ++e) wv[e] = w[b * 16 + e];
#pragma unroll
    for (int rep = 0; rep < 2; ++rep) {
        const int j = rep * 256 + tid;
        float s = 0.f;
#pragma unroll
        for (int e = 0; e < 16; ++e) s += wv[e] * b2V[e * 512 + j];
        towerAcc[(long)b * 512 + j] = s;
    }
}

// --- final heads: GEMV vs W2T (float4 streams), squash, logp ---------------
__global__ void head_kernel2(
    const f16* __restrict__ Rh, const f16* __restrict__ Rl,
    const float* __restrict__ W2T,   // [2][32][512]
    const float* __restrict__ mb2, const float* __restrict__ lb2,
    const float* __restrict__ eps, float* __restrict__ pi, float* __restrict__ logp) {
    __shared__ float src[4][1032];
    const int tid = threadIdx.x, l = tid & 63, w = tid >> 6;
    const int b = blockIdx.x * 4 + w;  // one wave per row
    const long rb = (long)b * 1024;
    {
        f16x8 h0 = *(const f16x8*)&Rh[rb + l * 8];
        f16x8 l0 = *(const f16x8*)&Rl[rb + l * 8];
        f16x8 h1 = *(const f16x8*)&Rh[rb + 512 + l * 8];
        f16x8 l1 = *(const f16x8*)&Rl[rb + 512 + l * 8];
#pragma unroll
        for (int j = 0; j < 8; ++j) {
            src[w][l * 8 + j] = (float)h0[j] + (float)l0[j];
            src[w][512 + l * 8 + j] = (float)h1[j] + (float)l1[j];
        }
    }
    __syncthreads();
    const int col = l & 31;
    const int half = l >> 5;  // 0 = mu, 1 = log_std
    const float4* wp = (const float4*)(W2T + ((long)(half * 32 + col)) * 512);
    const float4* sp = (const float4*)(&src[w][half * 512]);
    float a0 = 0.f, a1 = 0.f, a2 = 0.f, a3 = 0.f;
#pragma unroll 8
    for (int k4 = 0; k4 < 128; ++k4) {
        const float4 wv = wp[k4];
        const float4 sv = sp[k4];
        a0 = fmaf(wv.x, sv.x, a0);
        a1 = fmaf(wv.y, sv.y, a1);
        a2 = fmaf(wv.z, sv.z, a2);
        a3 = fmaf(wv.w, sv.w, a3);
    }
    const float* b2 = half ? lb2 : mb2;
    float s = b2[col] + ((a0 + a1) + (a2 + a3));
    const float other = __shfl_xor(s, 32);  // swap mu <-> log_std halves
    if (half == 0) {
        const float mu = s;
        float ls = fminf(fmaxf(other, -20.f), 2.f);
        const float e = eps[(long)b * 32 + col];
        const float a = mu + expf(ls) * e;
        float lt = -0.5f * e * e - ls - 0.91893853320467274f;  // -0.5*log(2*pi)
        const float x = -2.f * a;
        const float sp2 = fmaxf(x, 0.f) + log1pf(expf(-fabsf(x)));
        lt -= 2.f * (0.69314718055994531f - a - sp2);
        pi[(long)b * 32 + col] = tanhf(a);
        float r = lt;
#pragma unroll
        for (int d = 1; d < 32; d <<= 1) r += __shfl_xor(r, d);
        if (col == 0) logp[b] = r;
    }
}

// ---------------------------------------------------------------------------
extern "C" void kernel_launch(void* const* d_in, const int* in_sizes, int n_in,
                              void* d_out, int out_size, void* d_ws, size_t ws_size,
                              hipStream_t stream) {
    const float* obs = (const float*)d_in[0];
    const int* task = (const int*)d_in[1];
    const float* eps = (const float*)d_in[2];
    const float* bW1 = (const float*)d_in[3];
    const float* bb1 = (const float*)d_in[4];
    const float* bW2 = (const float*)d_in[5];
    const float* bb2 = (const float*)d_in[6];
    const float* eW1 = (const float*)d_in[7];
    const float* eb1 = (const float*)d_in[8];
    const float* eW2 = (const float*)d_in[9];
    const float* eb2 = (const float*)d_in[10];
    const float* keyM = (const float*)d_in[11];
    const float* valM = (const float*)d_in[12];
    const float* tq = (const float*)d_in[13];
    const float* mW1 = (const float*)d_in[14];
    const float* mb1 = (const float*)d_in[15];
    const float* mW2 = (const float*)d_in[16];
    const float* mb2 = (const float*)d_in[17];
    const float* lW1 = (const float*)d_in[18];
    const float* lb1 = (const float*)d_in[19];
    const float* lW2 = (const float*)d_in[20];
    const float* lb2 = (const float*)d_in[21];
    (void)in_sizes; (void)n_in; (void)out_size; (void)ws_size;

    // ---- workspace map (base 122 MB + 128 MB U; ws >= 251 MB verified R4) --
    const size_t MB = 1u << 20, KB = 1u << 10;
    char* base = (char*)d_ws;
    f16* eW1t_h = (f16*)(base + 0 * MB);   f16* eW1t_l = (f16*)(base + 8 * MB);
    f16* Wv2_h  = (f16*)(base + 16 * MB);  // [j2][(e,i)] single f16
    f16* eW2s_h = (f16*)(base + 32 * MB);  f16* eW2s_l = (f16*)(base + 40 * MB);
    f16* h2_h   = (f16*)(base + 32 * MB);  f16* h2_l   = (f16*)(base + 40 * MB);  // after folds
    f16* t1_h   = (f16*)(base + 48 * MB);  f16* t1_l   = (f16*)(base + 56 * MB);
    f16* Rcat_l = (f16*)(base + 48 * MB);                                         // heads (t1 dead)
    f16* Vt_h   = (f16*)(base + 64 * MB);  f16* Vt_l   = (f16*)(base + 72 * MB);
    f16* Rcat_h = (f16*)(base + 64 * MB);                                         // heads (Vt dead)
    // 80-112 MB region, phase 1 (KQ path): keyM pairs, KqT, tqP, KQ2
    f16* keyMs_h = (f16*)(base + 80 * MB); f16* keyMs_l = (f16*)(base + 88 * MB);
    f16* KqT_h   = (f16*)(base + 96 * MB); f16* KqT_l   = (f16*)(base + 98 * MB); // [128][8192]
    f16* tqP_h   = (f16*)(base + 100 * MB); f16* tqP_l  = (f16*)(base + 101 * MB); // [128][512]
    float* KQ2   = (float*)(base + 104 * MB);                                     // [128][16][512] f32
    // 80-112 MB region, phase 2 (tower/heads): towerAcc (wb), twP
    float* towerAcc = (float*)(base + 80 * MB);                                   // 16 MB
    f16* twP_h  = (f16*)(base + 96 * MB);  f16* twP_l  = (f16*)(base + 104 * MB);
    f16* obs_h  = (f16*)(base + 112 * MB); f16* obs_l  = (f16*)(base + 114 * MB);
    char* q = base + 116 * MB;
    f16* bW1t_h = (f16*)q; q += 128 * KB;  f16* bW1t_l = (f16*)q; q += 128 * KB;
    f16* bW2t_h = (f16*)q; q += 512 * KB;  f16* bW2t_l = (f16*)q; q += 512 * KB;
    // order m_h, l_h, m_l, l_l so the z=2 head GEMM can stride (zsB = 262144)
    f16* mW1t_h = (f16*)q; q += 512 * KB;
    f16* lW1t_h = (f16*)q; q += 512 * KB;
    f16* mW1t_l = (f16*)q; q += 512 * KB;
    f16* lW1t_l = (f16*)q; q += 512 * KB;
    float* scores = (float*)q; q += 512 * KB;    // 8192*16 f32 (becomes w)
    float* b2V    = (float*)q; q += 32 * KB;
    float* cb     = (float*)q; q += 16 * KB;
    float* W2T    = (float*)q; q += 128 * KB;    // [2][32][512]
    float* bcat   = (float*)q; q += 16 * KB;     // [2][512]
    f16* U = (f16*)(base + 122 * MB);            // [8192][8192] single f16

    const long EST = 262144;  // per-expert 512x512 stride

    // ---- 1) splits / transposes ----
    split_pairs<<<1024, 256, 0, stream>>>(obs, obs_h, obs_l, 262144);
    split_pairs<<<4096, 256, 0, stream>>>(eW2, eW2s_h, eW2s_l, 1048576);
    split_pairs<<<4096, 256, 0, stream>>>(keyM, keyMs_h, keyMs_l, 1048576);
    hipMemsetAsync(tqP_h, 0, 128 * 512 * sizeof(f16), stream);
    hipMemsetAsync(tqP_l, 0, 128 * 512 * sizeof(f16), stream);
    split_pairs<<<25, 256, 0, stream>>>(tq, tqP_h, tqP_l, 6400);
    transpose_split<<<dim3(4, 16, 1), 256, 0, stream>>>(bW1, bW1t_h, bW1t_l, 128, 512, 0, 0);
    transpose_split<<<dim3(16, 16, 1), 256, 0, stream>>>(bW2, bW2t_h, bW2t_l, 512, 512, 0, 0);
    transpose_split<<<dim3(16, 16, 1), 256, 0, stream>>>(mW1, mW1t_h, mW1t_l, 512, 512, 0, 0);
    transpose_split<<<dim3(16, 16, 1), 256, 0, stream>>>(lW1, lW1t_h, lW1t_l, 512, 512, 0, 0);
    transpose_split<<<dim3(16, 16, 16), 256, 0, stream>>>(eW1, eW1t_h, eW1t_l, 512, 512, EST, EST);
    transpose_split<<<dim3(16, 16, 16), 256, 0, stream>>>(valM, Vt_h, Vt_l, 512, 512, EST, EST);
    build_w2t<<<128, 256, 0, stream>>>(mW2, lW2, W2T);
    build_bcat<<<4, 256, 0, stream>>>(mb1, lb1, bcat);

    // ---- 2) attention folds ----
    // Wv2[j2][(e,i)] = (eW2@V)[i][j2]  (single-f16 transposed write)
    gemm_pair<7, false, false, false><<<dim3(8, 4, 16), 256, 0, stream>>>(
        eW2s_h, eW2s_l, 512, EST, Vt_h, Vt_l, 512, EST, nullptr, 0,
        Wv2_h, nullptr, nullptr, 8192, 512, 512, nullptr, nullptr, nullptr, nullptr);
    // KqT[t][(e,k)] = (keyM @ tq^T)[(e,k)][t]   (N=128 padded, pair transposed)
    gemm_pair<1, false, false, false><<<dim3(128, 1, 1), 256, 0, stream>>>(
        keyMs_h, keyMs_l, 512, 0, tqP_h, tqP_l, 512, 0, nullptr, 0,
        KqT_h, KqT_l, nullptr, 8192, 0, 512, nullptr, nullptr, nullptr, nullptr);
    // KQ2[(t,e)][i] = (eW2_e @ KqT_e^T)[i][t]   (f32 transposed write)
    gemm_pair<6, false, false, false><<<dim3(8, 1, 16), 256, 0, stream>>>(
        eW2s_h, eW2s_l, 512, EST, KqT_h, KqT_l, 8192, 512, nullptr, 0,
        nullptr, nullptr, KQ2, 8192, 512, 512, nullptr, nullptr, nullptr, nullptr);
    cb_from_kq<<<200, 256, 0, stream>>>(KqT_h, KqT_l, eb2, cb);
    bias_fold<<<32, 256, 0, stream>>>(eb2, valM, b2V);

    // ---- 3) backbone ----
    gemm_pair<0, true, false, false><<<dim3(128, 4, 1), 256, 0, stream>>>(
        obs_h, obs_l, 128, 0, bW1t_h, bW1t_l, 128, 0, bb1, 0,
        t1_h, t1_l, nullptr, 512, 0, 128, nullptr, nullptr, nullptr, nullptr);
    gemm_pair<0, true, false, false><<<dim3(128, 4, 1), 256, 0, stream>>>(
        t1_h, t1_l, 512, 0, bW2t_h, bW2t_l, 512, 0, bb2, 0,
        h2_h, h2_l, nullptr, 512, 0, 512, nullptr, nullptr, nullptr, nullptr);

    // ---- 4) pass A: one flat M=8192 x N=8192 GEMM; scores + U ----
    scores_init<<<512, 256, 0, stream>>>(task, cb, scores);
    gemm_pair<5, true, false, false><<<dim3(128, 64, 1), 256, 0, stream>>>(
        h2_h, h2_l, 512, 0, eW1t_h, eW1t_l, 512, 0, eb1, 0,
        U, nullptr, nullptr, 8192, 0, 512, nullptr, task, KQ2, scores);
    softmax16<<<32, 256, 0, stream>>>(scores);

    // ---- 5) tower: twP = wb + (w .* U) @ Wv2  (plain 1-MFMA GEMM; wb input,
    //         softmax scale fused in A staging, pair-split fused in epilogue) --
    wb_init<<<8192, 256, 0, stream>>>(scores, b2V, towerAcc);
    gemm_pair<8, false, true, true><<<dim3(128, 4, 1), 256, 0, stream>>>(
        U, nullptr, 8192, 0, Wv2_h, nullptr, 8192, 0, nullptr, 0,
        twP_h, twP_l, towerAcc, 512, 0, 8192, scores, nullptr, nullptr, nullptr);

    // ---- 6) heads: layer-1 into Rcat [8192][1024] (z=2), fused GEMV+squash --
    gemm_pair<0, true, false, false><<<dim3(128, 4, 2), 256, 0, stream>>>(
        twP_h, twP_l, 512, 0, mW1t_h, mW1t_l, 512, 262144, bcat, 512,
        Rcat_h, Rcat_l, nullptr, 1024, 512, 512, nullptr, nullptr, nullptr, nullptr);
    head_kernel2<<<2048, 256, 0, stream>>>(Rcat_h, Rcat_l, W2T, mb2, lb2, eps,
                                           (float*)d_out, (float*)d_out + 262144);
}

// Round 8
// 663.921 us; speedup vs baseline: 1.5193x; 1.0624x over previous
//
#include <hip/hip_runtime.h>
#include <hip/hip_bf16.h>
#include <cstdint>

// ---------------------------------------------------------------------------
// SquashedGaussianMoEActor forward, MI355X (gfx950).
// Split-f16 MFMA (hi/lo pairs, 3x v_mfma_f32_16x16x32_f16) = fp32-quality on
// the score path (softmax-over-experts is flip-sensitive); single-f16 on the
// tower path (error budget verified: absmax 4.0 / threshold 14.56 at R6/R7).
// R8: precision-matched MFMA counts -- Wv2 fold 2-MFMA, heads layer-1 1-MFMA
// (tower is already single-f16; finer correction is below output rounding).
// B=8192, OBS=128, H=D=512, E=16, T=50, A=32.
// ---------------------------------------------------------------------------

typedef _Float16 f16;
typedef _Float16 f16x4 __attribute__((ext_vector_type(4)));
typedef _Float16 f16x8 __attribute__((ext_vector_type(8)));
typedef float f32x4 __attribute__((ext_vector_type(4)));

__device__ __forceinline__ void fsplit(float x, f16& h, f16& l) {
    h = (f16)x;
    l = (f16)(x - (float)h);
}

__device__ __forceinline__ void gload16(const void* g, void* s) {
    __builtin_amdgcn_global_load_lds(
        (const __attribute__((address_space(1))) void*)g,
        (__attribute__((address_space(3))) void*)s, 16, 0, 0);
}

// --- elementwise fp32 -> f16 pair split -----------------------------------
__global__ void split_pairs(const float* __restrict__ x, f16* __restrict__ h,
                            f16* __restrict__ l, int n4) {
    int i = blockIdx.x * 256 + threadIdx.x;
    if (i >= n4) return;
    float4 v = ((const float4*)x)[i];
    float a[4] = {v.x, v.y, v.z, v.w};
    f16x4 hh, ll;
#pragma unroll
    for (int j = 0; j < 4; ++j) { f16 hj, lj; fsplit(a[j], hj, lj); hh[j] = hj; ll[j] = lj; }
    *(f16x4*)&h[(long)i * 4] = hh;
    *(f16x4*)&l[(long)i * 4] = ll;
}

// --- transpose [K,N] fp32 -> [N,K] f16 pairs (batched via z) ---------------
__global__ void transpose_split(const float* __restrict__ W, f16* __restrict__ Th,
                                f16* __restrict__ Tl, int K, int N, long ist, long ost) {
    __shared__ float t[32][33];
    const float* Wb = W + (long)blockIdx.z * ist;
    const int k0 = blockIdx.x * 32, n0 = blockIdx.y * 32;
    const int tid = threadIdx.x;
    const int r = tid >> 3, c4 = (tid & 7) * 4;
    float4 v = *(const float4*)&Wb[(long)(k0 + r) * N + n0 + c4];
    t[r][c4] = v.x; t[r][c4 + 1] = v.y; t[r][c4 + 2] = v.z; t[r][c4 + 3] = v.w;
    __syncthreads();
    f16x4 hh, ll;
#pragma unroll
    for (int j = 0; j < 4; ++j) { f16 hj, lj; fsplit(t[c4 + j][r], hj, lj); hh[j] = hj; ll[j] = lj; }
    long ob = (long)blockIdx.z * ost + (long)(n0 + r) * K + k0 + c4;
    *(f16x4*)&Th[ob] = hh;
    *(f16x4*)&Tl[ob] = ll;
}

// --- W2T[half][col][k]: [0]=mW2^T, [1]=lW2^T (f32) -------------------------
__global__ void build_w2t(const float* __restrict__ mW2, const float* __restrict__ lW2,
                          float* __restrict__ W2T) {
    const int i = blockIdx.x * 256 + threadIdx.x;  // 32768
    const int half = i >> 14, col = (i >> 9) & 31, k = i & 511;
    const float* src = half ? lW2 : mW2;
    W2T[i] = src[k * 32 + col];
}

// --- bcat = [mb1 ; lb1] ----------------------------------------------------
__global__ void build_bcat(const float* __restrict__ mb1, const float* __restrict__ lb1,
                           float* __restrict__ bcat) {
    const int i = blockIdx.x * 256 + threadIdx.x;  // 1024
    bcat[i] = (i < 512) ? mb1[i] : lb1[i - 512];
}

// --- split-f16 GEMM: C = act(A @ B^T_stored + bias) ------------------------
// Tile 64x128, BK=64, 4 waves each owning 32x64 (2x4 frags of 16x16x32).
// Staging via global_load_lds (linear LDS dest, pre-swizzled global source;
// read side applies the same chunk^=row&7 involution). Single-buffered,
// 3-4 blocks/CU -- inter-block overlap hides barrier drains (m114).
// OUTM: 0 pair write, 1 pair write transposed, 2 f32 write, 3 f32 accum,
//       5 score mode (flat expert=col0>>9; row-dot KQ2 -> atomicAdd) + write
//         t1 single-f16 to Ch (U buffer), 6 f32 write transposed,
//       7 single-f16 write transposed, 8 single-f16 write w/ f32 C-in (Cf).
// AMODE: 0 = A pair (gload, 3rd MFMA), 1 = A single (gload),
//        2 = A single reg-staged with fused per-(row, ktile) wscale.
// BSINGLE: B single plane (skips the AhBl MFMA).
template <int OUTM, bool RELU, int AMODE, bool BSINGLE>
__global__ __launch_bounds__(256, AMODE == 0 ? 3 : 4) void gemm_pair(
    const f16* __restrict__ Ah, const f16* __restrict__ Al, int lda, long zsA,
    const f16* __restrict__ Bh, const f16* __restrict__ Bl, int ldb, long zsB,
    const float* __restrict__ bias, long zsBias,
    f16* __restrict__ Ch, f16* __restrict__ Cl, float* __restrict__ Cf,
    int ldc, long zsC, int K,
    const float* __restrict__ wscale,
    const int* __restrict__ task, const float* __restrict__ KQ2,
    float* __restrict__ scores) {
    __shared__ f16 As[AMODE == 0 ? 2 : 1][64][64];
    __shared__ f16 Bs[BSINGLE ? 1 : 2][128][64];
    const int z = blockIdx.z;
    Ah += (long)z * zsA;
    if constexpr (AMODE == 0) Al += (long)z * zsA;
    Bh += (long)z * zsB;
    if constexpr (!BSINGLE) Bl += (long)z * zsB;
    if (bias) bias += (long)z * zsBias;
    if (OUTM <= 1) { Ch += (long)z * zsC; Cl += (long)z * zsC; }
    if (OUTM == 7) { Ch += (long)z * zsC; }
    if (OUTM == 2 || OUTM == 3 || OUTM == 6) { Cf += (long)z * zsC; }
    const int tid = threadIdx.x;
    const int l = tid & 63;
    const int w = tid >> 6;
    const int row0 = blockIdx.x * 64;
    const int col0 = blockIdx.y * 128;
    const int wr = (w >> 1) * 32;
    const int wc = (w & 1) * 64;
    const int grow = l >> 3;           // row within 8-row group
    const int gch = (l & 7) ^ grow;    // pre-swizzled k-chunk for gload_lds

    f32x4 acc[2][4];
#pragma unroll
    for (int mi = 0; mi < 2; ++mi)
#pragma unroll
        for (int ni = 0; ni < 4; ++ni)
#pragma unroll
            for (int j = 0; j < 4; ++j) acc[mi][ni][j] = 0.f;

    // AMODE==2: reg-staged A with fused per-(row, ktile) scale
    uint4 areg0, areg1; float ascl0, ascl1;
    auto ldA = [&](int k0) {
        const int r0 = w * 16 + grow, r1 = r0 + 8;
        const int scl = l & 7;
        areg0 = *(const uint4*)&Ah[(long)(row0 + r0) * lda + k0 + scl * 8];
        areg1 = *(const uint4*)&Ah[(long)(row0 + r1) * lda + k0 + scl * 8];
        const int e = k0 >> 9;
        ascl0 = wscale[(long)(row0 + r0) * 16 + e];
        ascl1 = wscale[(long)(row0 + r1) * 16 + e];
    };
    auto wrA = [&]() {
        const int scl = l & 7;
#pragma unroll
        for (int h = 0; h < 2; ++h) {
            const int r = w * 16 + grow + h * 8;
            const float s = h ? ascl1 : ascl0;
            f16x8 v = h ? *(f16x8*)&areg1 : *(f16x8*)&areg0;
#pragma unroll
            for (int j = 0; j < 8; ++j) v[j] = (f16)((float)v[j] * s);
            *(uint4*)&As[0][r][(scl ^ (r & 7)) * 8] = *(uint4*)&v;
        }
    };

    if constexpr (AMODE == 2) ldA(0);
    for (int k0 = 0; k0 < K; k0 += 64) {
        __syncthreads();
        if constexpr (AMODE == 2) {
            wrA();
            if (k0 + 64 < K) ldA(k0 + 64);  // next loads issued early (hidden under compute)
        } else {
            // A: wave w stages rows [w*16, w*16+16)
            const long ga = (long)(row0 + w * 16 + grow) * lda + k0 + gch * 8;
            gload16(Ah + ga, &As[0][w * 16][0]);
            gload16(Ah + ga + (long)8 * lda, &As[0][w * 16 + 8][0]);
            if constexpr (AMODE == 0) {
                gload16(Al + ga, &As[1][w * 16][0]);
                gload16(Al + ga + (long)8 * lda, &As[1][w * 16 + 8][0]);
            }
        }
        {
            // B: wave w stages rows [w*32, w*32+32)
            const long gb = (long)(col0 + w * 32 + grow) * ldb + k0 + gch * 8;
            gload16(Bh + gb, &Bs[0][w * 32][0]);
            gload16(Bh + gb + (long)8 * ldb, &Bs[0][w * 32 + 8][0]);
            gload16(Bh + gb + (long)16 * ldb, &Bs[0][w * 32 + 16][0]);
            gload16(Bh + gb + (long)24 * ldb, &Bs[0][w * 32 + 24][0]);
            if constexpr (!BSINGLE) {
                gload16(Bl + gb, &Bs[1][w * 32][0]);
                gload16(Bl + gb + (long)8 * ldb, &Bs[1][w * 32 + 8][0]);
                gload16(Bl + gb + (long)16 * ldb, &Bs[1][w * 32 + 16][0]);
                gload16(Bl + gb + (long)24 * ldb, &Bs[1][w * 32 + 24][0]);
            }
        }
        __syncthreads();
        const int r16 = l & 15, kg = l >> 4;
#pragma unroll
        for (int ks = 0; ks < 2; ++ks) {
            f16x8 a_h[2], a_l[2], b_h[4], b_l[4];
#pragma unroll
            for (int mi = 0; mi < 2; ++mi) {
                const int r = wr + mi * 16 + r16;
                const int off = ((ks * 4 + kg) ^ (r & 7)) * 8;
                a_h[mi] = *(const f16x8*)&As[0][r][off];
                if constexpr (AMODE == 0) a_l[mi] = *(const f16x8*)&As[1][r][off];
            }
#pragma unroll
            for (int ni = 0; ni < 4; ++ni) {
                const int c = wc + ni * 16 + r16;
                const int off = ((ks * 4 + kg) ^ (c & 7)) * 8;
                b_h[ni] = *(const f16x8*)&Bs[0][c][off];
                if constexpr (!BSINGLE) b_l[ni] = *(const f16x8*)&Bs[1][c][off];
            }
#pragma unroll
            for (int mi = 0; mi < 2; ++mi)
#pragma unroll
                for (int ni = 0; ni < 4; ++ni) {
                    acc[mi][ni] = __builtin_amdgcn_mfma_f32_16x16x32_f16(a_h[mi], b_h[ni], acc[mi][ni], 0, 0, 0);
                    if constexpr (!BSINGLE)
                        acc[mi][ni] = __builtin_amdgcn_mfma_f32_16x16x32_f16(a_h[mi], b_l[ni], acc[mi][ni], 0, 0, 0);
                    if constexpr (AMODE == 0)
                        acc[mi][ni] = __builtin_amdgcn_mfma_f32_16x16x32_f16(a_l[mi], b_h[ni], acc[mi][ni], 0, 0, 0);
                }
        }
    }
    // epilogue. C layout (m89-verified): col = lane&15, row = (lane>>4)*4 + reg.
    const int lane15 = l & 15;
    const int rsub = (l >> 4) * 4;
    if (OUTM == 5) {
        const int expert = col0 >> 9;
        float bv[4];
#pragma unroll
        for (int ni = 0; ni < 4; ++ni)
            bv[ni] = bias ? bias[col0 + wc + ni * 16 + lane15] : 0.f;
#pragma unroll
        for (int mi = 0; mi < 2; ++mi)
#pragma unroll
            for (int j = 0; j < 4; ++j) {
                const int rowg = row0 + wr + mi * 16 + rsub + j;
                const int t = task[rowg];
                const float* kqr = KQ2 + ((long)t * 16 + expert) * 512;
                float part = 0.f;
#pragma unroll
                for (int ni = 0; ni < 4; ++ni) {
                    const int colg = col0 + wc + ni * 16 + lane15;
                    float v = acc[mi][ni][j] + bv[ni];
                    if (RELU) v = fmaxf(v, 0.f);
                    Ch[(long)rowg * ldc + colg] = (f16)v;
                    part += v * kqr[colg & 511];
                }
#pragma unroll
                for (int d = 1; d < 16; d <<= 1) part += __shfl_xor(part, d);
                if (lane15 == 0) atomicAdd(&scores[rowg * 16 + expert], part);
            }
    } else {
#pragma unroll
        for (int mi = 0; mi < 2; ++mi)
#pragma unroll
            for (int ni = 0; ni < 4; ++ni) {
                const int colg = col0 + wc + ni * 16 + lane15;
                const float bv = bias ? bias[colg] : 0.f;
#pragma unroll
                for (int j = 0; j < 4; ++j) {
                    const int rowg = row0 + wr + mi * 16 + rsub + j;
                    float v = acc[mi][ni][j] + bv;
                    if (RELU) v = fmaxf(v, 0.f);
                    if (OUTM == 0) {
                        f16 hh, ll; fsplit(v, hh, ll);
                        const long idx = (long)rowg * ldc + colg;
                        Ch[idx] = hh; Cl[idx] = ll;
                    } else if (OUTM == 1) {
                        f16 hh, ll; fsplit(v, hh, ll);
                        const long idx = (long)colg * ldc + rowg;
                        Ch[idx] = hh; Cl[idx] = ll;
                    } else if (OUTM == 2) {
                        Cf[(long)rowg * ldc + colg] = v;
                    } else if (OUTM == 3) {
                        Cf[(long)rowg * ldc + colg] += v;
                    } else if (OUTM == 6) {
                        Cf[(long)colg * ldc + rowg] = v;
                    } else if (OUTM == 7) {
                        Ch[(long)colg * ldc + rowg] = (f16)v;
                    } else if (OUTM == 8) {
                        const long idx = (long)rowg * ldc + colg;
                        v += Cf[idx];   // wb input
                        Ch[idx] = (f16)v;
                    }
                }
            }
    }
}

// --- cb[t][e] = sum_k eb2[e,k] * Kq[e,k,t]  (from KqT pairs) ---------------
__global__ void cb_from_kq(const f16* __restrict__ KqT_h, const f16* __restrict__ KqT_l,
                           const float* __restrict__ eb2, float* __restrict__ cb) {
    const int gw = (blockIdx.x * 256 + threadIdx.x) >> 6;  // 0..799
    const int l = threadIdx.x & 63;
    const int t = gw >> 4, e = gw & 15;
    const long base = (long)t * 8192 + e * 512 + l * 8;
    f16x8 hh = *(const f16x8*)&KqT_h[base];
    f16x8 ll = *(const f16x8*)&KqT_l[base];
    const float* bb = eb2 + e * 512 + l * 8;
    float s = 0.f;
#pragma unroll
    for (int j = 0; j < 8; ++j) s += ((float)hh[j] + (float)ll[j]) * bb[j];
#pragma unroll
    for (int d = 1; d < 64; d <<= 1) s += __shfl_xor(s, d);
    if (l == 0) cb[t * 16 + e] = s;
}

// --- out[e*512+j] = sum_k bvec[e*512+k] * M[e][k][j] -----------------------
__global__ void bias_fold(const float* __restrict__ bvec, const float* __restrict__ M,
                          float* __restrict__ out) {
    const int gid = blockIdx.x * 256 + threadIdx.x;  // 8192
    const int e = gid >> 9, j = gid & 511;
    const float* Me = M + (long)e * 262144;
    const float* be = bvec + e * 512;
    float s = 0.f;
    for (int k = 0; k < 512; ++k) s += be[k] * Me[(long)k * 512 + j];
    out[gid] = s;
}

// --- scores[b*16+e] = cb[task[b]*16+e] -------------------------------------
__global__ void scores_init(const int* __restrict__ task, const float* __restrict__ cb,
                            float* __restrict__ sc) {
    const int i = blockIdx.x * 256 + threadIdx.x;  // 131072
    sc[i] = cb[task[i >> 4] * 16 + (i & 15)];
}

// --- in-place softmax over E=16 per row ------------------------------------
__global__ void softmax16(float* __restrict__ sc) {
    const int b = blockIdx.x * 256 + threadIdx.x;  // 8192
    float v[16];
    const float4* pp = (const float4*)&sc[b * 16];
#pragma unroll
    for (int qq = 0; qq < 4; ++qq) {
        float4 t = pp[qq];
        v[qq * 4] = t.x; v[qq * 4 + 1] = t.y; v[qq * 4 + 2] = t.z; v[qq * 4 + 3] = t.w;
    }
    float m = v[0];
#pragma unroll
    for (int e = 1; e < 16; ++e) m = fmaxf(m, v[e]);
    float ssum = 0.f;
#pragma unroll
    for (int e = 0; e < 16; ++e) { v[e] = expf(v[e] - m); ssum += v[e]; }
    const float inv = 1.f / ssum;
    float4* o = (float4*)&sc[b * 16];
#pragma unroll
    for (int qq = 0; qq < 4; ++qq) {
        float4 t;
        t.x = v[qq * 4] * inv; t.y = v[qq * 4 + 1] * inv;
        t.z = v[qq * 4 + 2] * inv; t.w = v[qq * 4 + 3] * inv;
        o[qq] = t;
    }
}

// --- towerAcc[b][j] = sum_e w[b][e] * b2V[e][j] ----------------------------
__global__ void wb_init(const float* __restrict__ w, const float* __restrict__ b2V,
                        float* __restrict__ towerAcc) {
    const int b = blockIdx.x;
    const int tid = threadIdx.x;
    float wv[16];
#pragma unroll
    for (int e = 0; e < 16; ++e) wv[e] = w[b * 16 + e];
#pragma unroll
    for (int rep = 0; rep < 2; ++rep) {
        const int j = rep * 256 + tid;
        float s = 0.f;
#pragma unroll
        for (int e = 0; e < 16; ++e) s += wv[e] * b2V[e * 512 + j];
        towerAcc[(long)b * 512 + j] = s;
    }
}

// --- final heads: GEMV vs W2T (float4 streams), squash, logp ---------------
__global__ void head_kernel2(
    const f16* __restrict__ Rh, const f16* __restrict__ Rl,
    const float* __restrict__ W2T,   // [2][32][512]
    const float* __restrict__ mb2, const float* __restrict__ lb2,
    const float* __restrict__ eps, float* __restrict__ pi, float* __restrict__ logp) {
    __shared__ float src[4][1032];
    const int tid = threadIdx.x, l = tid & 63, w = tid >> 6;
    const int b = blockIdx.x * 4 + w;  // one wave per row
    const long rb = (long)b * 1024;
    {
        f16x8 h0 = *(const f16x8*)&Rh[rb + l * 8];
        f16x8 l0 = *(const f16x8*)&Rl[rb + l * 8];
        f16x8 h1 = *(const f16x8*)&Rh[rb + 512 + l * 8];
        f16x8 l1 = *(const f16x8*)&Rl[rb + 512 + l * 8];
#pragma unroll
        for (int j = 0; j < 8; ++j) {
            src[w][l * 8 + j] = (float)h0[j] + (float)l0[j];
            src[w][512 + l * 8 + j] = (float)h1[j] + (float)l1[j];
        }
    }
    __syncthreads();
    const int col = l & 31;
    const int half = l >> 5;  // 0 = mu, 1 = log_std
    const float4* wp = (const float4*)(W2T + ((long)(half * 32 + col)) * 512);
    const float4* sp = (const float4*)(&src[w][half * 512]);
    float a0 = 0.f, a1 = 0.f, a2 = 0.f, a3 = 0.f;
#pragma unroll 8
    for (int k4 = 0; k4 < 128; ++k4) {
        const float4 wv = wp[k4];
        const float4 sv = sp[k4];
        a0 = fmaf(wv.x, sv.x, a0);
        a1 = fmaf(wv.y, sv.y, a1);
        a2 = fmaf(wv.z, sv.z, a2);
        a3 = fmaf(wv.w, sv.w, a3);
    }
    const float* b2 = half ? lb2 : mb2;
    float s = b2[col] + ((a0 + a1) + (a2 + a3));
    const float other = __shfl_xor(s, 32);  // swap mu <-> log_std halves
    if (half == 0) {
        const float mu = s;
        float ls = fminf(fmaxf(other, -20.f), 2.f);
        const float e = eps[(long)b * 32 + col];
        const float a = mu + expf(ls) * e;
        float lt = -0.5f * e * e - ls - 0.91893853320467274f;  // -0.5*log(2*pi)
        const float x = -2.f * a;
        const float sp2 = fmaxf(x, 0.f) + log1pf(expf(-fabsf(x)));
        lt -= 2.f * (0.69314718055994531f - a - sp2);
        pi[(long)b * 32 + col] = tanhf(a);
        float r = lt;
#pragma unroll
        for (int d = 1; d < 32; d <<= 1) r += __shfl_xor(r, d);
        if (col == 0) logp[b] = r;
    }
}

// ---------------------------------------------------------------------------
extern "C" void kernel_launch(void* const* d_in, const int* in_sizes, int n_in,
                              void* d_out, int out_size, void* d_ws, size_t ws_size,
                              hipStream_t stream) {
    const float* obs = (const float*)d_in[0];
    const int* task = (const int*)d_in[1];
    const float* eps = (const float*)d_in[2];
    const float* bW1 = (const float*)d_in[3];
    const float* bb1 = (const float*)d_in[4];
    const float* bW2 = (const float*)d_in[5];
    const float* bb2 = (const float*)d_in[6];
    const float* eW1 = (const float*)d_in[7];
    const float* eb1 = (const float*)d_in[8];
    const float* eW2 = (const float*)d_in[9];
    const float* eb2 = (const float*)d_in[10];
    const float* keyM = (const float*)d_in[11];
    const float* valM = (const float*)d_in[12];
    const float* tq = (const float*)d_in[13];
    const float* mW1 = (const float*)d_in[14];
    const float* mb1 = (const float*)d_in[15];
    const float* mW2 = (const float*)d_in[16];
    const float* mb2 = (const float*)d_in[17];
    const float* lW1 = (const float*)d_in[18];
    const float* lb1 = (const float*)d_in[19];
    const float* lW2 = (const float*)d_in[20];
    const float* lb2 = (const float*)d_in[21];
    (void)in_sizes; (void)n_in; (void)out_size; (void)ws_size;

    // ---- workspace map (base 122 MB + 128 MB U; ws >= 251 MB verified R4) --
    const size_t MB = 1u << 20, KB = 1u << 10;
    char* base = (char*)d_ws;
    f16* eW1t_h = (f16*)(base + 0 * MB);   f16* eW1t_l = (f16*)(base + 8 * MB);
    f16* Wv2_h  = (f16*)(base + 16 * MB);  // [j2][(e,i)] single f16
    f16* eW2s_h = (f16*)(base + 32 * MB);  f16* eW2s_l = (f16*)(base + 40 * MB);
    f16* h2_h   = (f16*)(base + 32 * MB);  f16* h2_l   = (f16*)(base + 40 * MB);  // after folds
    f16* t1_h   = (f16*)(base + 48 * MB);  f16* t1_l   = (f16*)(base + 56 * MB);
    f16* Rcat_l = (f16*)(base + 48 * MB);                                         // heads (t1 dead)
    f16* Vt_h   = (f16*)(base + 64 * MB);  f16* Vt_l   = (f16*)(base + 72 * MB);
    f16* Rcat_h = (f16*)(base + 64 * MB);                                         // heads (Vt dead)
    // 80-112 MB region, phase 1 (KQ path): keyM pairs, KqT, tqP, KQ2
    f16* keyMs_h = (f16*)(base + 80 * MB); f16* keyMs_l = (f16*)(base + 88 * MB);
    f16* KqT_h   = (f16*)(base + 96 * MB); f16* KqT_l   = (f16*)(base + 98 * MB); // [128][8192]
    f16* tqP_h   = (f16*)(base + 100 * MB); f16* tqP_l  = (f16*)(base + 100 * MB + 128 * KB); // [128][512]
    float* KQ2   = (float*)(base + 104 * MB);                                     // [128][16][512] f32
    // 80-112 MB region, phase 2 (tower/heads): towerAcc (wb), twP (single)
    float* towerAcc = (float*)(base + 80 * MB);                                   // 16 MB
    f16* twP_h  = (f16*)(base + 96 * MB);
    f16* obs_h  = (f16*)(base + 112 * MB); f16* obs_l  = (f16*)(base + 114 * MB);
    char* q = base + 116 * MB;
    f16* bW1t_h = (f16*)q; q += 128 * KB;  f16* bW1t_l = (f16*)q; q += 128 * KB;
    f16* bW2t_h = (f16*)q; q += 512 * KB;  f16* bW2t_l = (f16*)q; q += 512 * KB;
    // order m_h, l_h, m_l, l_l so the z=2 head GEMM can stride (zsB = 262144)
    f16* mW1t_h = (f16*)q; q += 512 * KB;
    f16* lW1t_h = (f16*)q; q += 512 * KB;
    f16* mW1t_l = (f16*)q; q += 512 * KB;
    f16* lW1t_l = (f16*)q; q += 512 * KB;
    float* scores = (float*)q; q += 512 * KB;    // 8192*16 f32 (becomes w)
    float* b2V    = (float*)q; q += 32 * KB;
    float* cb     = (float*)q; q += 16 * KB;
    float* W2T    = (float*)q; q += 128 * KB;    // [2][32][512]
    float* bcat   = (float*)q; q += 16 * KB;     // [2][512]
    f16* U = (f16*)(base + 122 * MB);            // [8192][8192] single f16

    const long EST = 262144;  // per-expert 512x512 stride

    // ---- 1) splits / transposes ----
    split_pairs<<<1024, 256, 0, stream>>>(obs, obs_h, obs_l, 262144);
    split_pairs<<<4096, 256, 0, stream>>>(eW2, eW2s_h, eW2s_l, 1048576);
    split_pairs<<<4096, 256, 0, stream>>>(keyM, keyMs_h, keyMs_l, 1048576);
    hipMemsetAsync(tqP_h, 0, 256 * KB, stream);  // tqP_h and tqP_l contiguous
    split_pairs<<<25, 256, 0, stream>>>(tq, tqP_h, tqP_l, 6400);
    transpose_split<<<dim3(4, 16, 1), 256, 0, stream>>>(bW1, bW1t_h, bW1t_l, 128, 512, 0, 0);
    transpose_split<<<dim3(16, 16, 1), 256, 0, stream>>>(bW2, bW2t_h, bW2t_l, 512, 512, 0, 0);
    transpose_split<<<dim3(16, 16, 1), 256, 0, stream>>>(mW1, mW1t_h, mW1t_l, 512, 512, 0, 0);
    transpose_split<<<dim3(16, 16, 1), 256, 0, stream>>>(lW1, lW1t_h, lW1t_l, 512, 512, 0, 0);
    transpose_split<<<dim3(16, 16, 16), 256, 0, stream>>>(eW1, eW1t_h, eW1t_l, 512, 512, EST, EST);
    transpose_split<<<dim3(16, 16, 16), 256, 0, stream>>>(valM, Vt_h, Vt_l, 512, 512, EST, EST);
    build_w2t<<<128, 256, 0, stream>>>(mW2, lW2, W2T);
    build_bcat<<<4, 256, 0, stream>>>(mb1, lb1, bcat);

    // ---- 2) attention folds ----
    // Wv2[j2][(e,i)] = (eW2@V)[i][j2]  (single-f16 out -> 2-MFMA: A pair x B single)
    gemm_pair<7, false, 0, true><<<dim3(8, 4, 16), 256, 0, stream>>>(
        eW2s_h, eW2s_l, 512, EST, Vt_h, nullptr, 512, EST, nullptr, 0,
        Wv2_h, nullptr, nullptr, 8192, 512, 512, nullptr, nullptr, nullptr, nullptr);
    // KqT[t][(e,k)] = (keyM @ tq^T)[(e,k)][t]   (N=128 padded, pair transposed)
    gemm_pair<1, false, 0, false><<<dim3(128, 1, 1), 256, 0, stream>>>(
        keyMs_h, keyMs_l, 512, 0, tqP_h, tqP_l, 512, 0, nullptr, 0,
        KqT_h, KqT_l, nullptr, 8192, 0, 512, nullptr, nullptr, nullptr, nullptr);
    // KQ2[(t,e)][i] = (eW2_e @ KqT_e^T)[i][t]   (f32 transposed write)
    gemm_pair<6, false, 0, false><<<dim3(8, 1, 16), 256, 0, stream>>>(
        eW2s_h, eW2s_l, 512, EST, KqT_h, KqT_l, 8192, 512, nullptr, 0,
        nullptr, nullptr, KQ2, 8192, 512, 512, nullptr, nullptr, nullptr, nullptr);
    cb_from_kq<<<200, 256, 0, stream>>>(KqT_h, KqT_l, eb2, cb);
    bias_fold<<<32, 256, 0, stream>>>(eb2, valM, b2V);

    // ---- 3) backbone (full pair precision: feeds the score path) ----
    gemm_pair<0, true, 0, false><<<dim3(128, 4, 1), 256, 0, stream>>>(
        obs_h, obs_l, 128, 0, bW1t_h, bW1t_l, 128, 0, bb1, 0,
        t1_h, t1_l, nullptr, 512, 0, 128, nullptr, nullptr, nullptr, nullptr);
    gemm_pair<0, true, 0, false><<<dim3(128, 4, 1), 256, 0, stream>>>(
        t1_h, t1_l, 512, 0, bW2t_h, bW2t_l, 512, 0, bb2, 0,
        h2_h, h2_l, nullptr, 512, 0, 512, nullptr, nullptr, nullptr, nullptr);

    // ---- 4) pass A: one flat M=8192 x N=8192 GEMM; scores + U ----
    scores_init<<<512, 256, 0, stream>>>(task, cb, scores);
    gemm_pair<5, true, 0, false><<<dim3(128, 64, 1), 256, 0, stream>>>(
        h2_h, h2_l, 512, 0, eW1t_h, eW1t_l, 512, 0, eb1, 0,
        U, nullptr, nullptr, 8192, 0, 512, nullptr, task, KQ2, scores);
    softmax16<<<32, 256, 0, stream>>>(scores);

    // ---- 5) tower: twP = wb + (w .* U) @ Wv2  (1-MFMA GEMM; wb C-input,
    //         softmax scale fused in A staging, single-f16 out) ----
    wb_init<<<8192, 256, 0, stream>>>(scores, b2V, towerAcc);
    gemm_pair<8, false, 2, true><<<dim3(128, 4, 1), 256, 0, stream>>>(
        U, nullptr, 8192, 0, Wv2_h, nullptr, 8192, 0, nullptr, 0,
        twP_h, nullptr, towerAcc, 512, 0, 8192, scores, nullptr, nullptr, nullptr);

    // ---- 6) heads: layer-1 (single x single = 1 MFMA) into Rcat, GEMV+squash --
    gemm_pair<0, true, 1, true><<<dim3(128, 4, 2), 256, 0, stream>>>(
        twP_h, nullptr, 512, 0, mW1t_h, nullptr, 512, 262144, bcat, 512,
        Rcat_h, Rcat_l, nullptr, 1024, 512, 512, nullptr, nullptr, nullptr, nullptr);
    head_kernel2<<<2048, 256, 0, stream>>>(Rcat_h, Rcat_l, W2T, mb2, lb2, eps,
                                           (float*)d_out, (float*)d_out + 262144);
}